// Round 1
// baseline (365.766 us; speedup 1.0000x reference)
//
#include <hip/hip_runtime.h>
#include <hip/hip_bf16.h>

// ---------------- CSR build ----------------

__global__ void k_count(const int* __restrict__ dst, int* __restrict__ indeg, int E) {
    int e = blockIdx.x * 256 + threadIdx.x;
    if (e < E) atomicAdd(&indeg[dst[e]], 1);
}

// pass 1: per-1024-tile exclusive scan (256 thr x 4 elems), tile totals out
__global__ void k_scan1(const int* __restrict__ in, int* __restrict__ out,
                        int* __restrict__ sums, int n) {
    __shared__ int lds[256];
    const int t = threadIdx.x;
    const int base = blockIdx.x * 1024 + t * 4;
    int v0 = (base + 0 < n) ? in[base + 0] : 0;
    int v1 = (base + 1 < n) ? in[base + 1] : 0;
    int v2 = (base + 2 < n) ? in[base + 2] : 0;
    int v3 = (base + 3 < n) ? in[base + 3] : 0;
    const int tsum = v0 + v1 + v2 + v3;
    lds[t] = tsum;
    __syncthreads();
    #pragma unroll
    for (int off = 1; off < 256; off <<= 1) {
        int x = (t >= off) ? lds[t - off] : 0;
        __syncthreads();
        lds[t] += x;
        __syncthreads();
    }
    int excl = lds[t] - tsum;
    if (base + 0 < n) out[base + 0] = excl;  excl += v0;
    if (base + 1 < n) out[base + 1] = excl;  excl += v1;
    if (base + 2 < n) out[base + 2] = excl;  excl += v2;
    if (base + 3 < n) out[base + 3] = excl;
    if (t == 255) sums[blockIdx.x] = lds[255];
}

// pass 2: exclusive scan of tile sums (single block, up to 128 tiles)
__global__ void k_scan2(int* __restrict__ sums, int nt) {
    __shared__ int lds[128];
    const int t = threadIdx.x;
    int v = (t < nt) ? sums[t] : 0;
    lds[t] = v;
    __syncthreads();
    #pragma unroll
    for (int off = 1; off < 128; off <<= 1) {
        int x = (t >= off) ? lds[t - off] : 0;
        __syncthreads();
        lds[t] += x;
        __syncthreads();
    }
    if (t < nt) sums[t] = lds[t] - v;
}

// pass 3: add tile offsets; also produce dinv and the sentinel row_start[n]=E
__global__ void k_scan3_dinv(int* __restrict__ row_start, const int* __restrict__ sums,
                             const int* __restrict__ indeg, float* __restrict__ dinv,
                             int n, int E) {
    int i = blockIdx.x * 256 + threadIdx.x;
    if (i < n) {
        row_start[i] += sums[i >> 10];
        dinv[i] = rsqrtf((float)indeg[i] + 1.0f);   // +1 self-loop
    }
    if (i == 0) row_start[n] = E;
}

__global__ void k_fill(const int* __restrict__ src, const int* __restrict__ dst,
                       const float* __restrict__ dinv, const int* __restrict__ row_start,
                       int* __restrict__ cursor, int* __restrict__ edge_src,
                       float* __restrict__ edge_w, int E) {
    int e = blockIdx.x * 256 + threadIdx.x;
    if (e >= E) return;
    int s = src[e], d = dst[e];
    int pos = row_start[d] + atomicAdd(&cursor[d], 1);
    edge_src[pos] = s;
    edge_w[pos] = dinv[s];
}

// ---------------- fp32 GEMM: C[M x 128] = A[M x 128] * B[128 x 128] ----------------
// 128x128 tile per block, 256 threads, 8x8 per thread as 2x2 blocks of 4x4.

__global__ __launch_bounds__(256) void k_gemm128(const float* __restrict__ A,
                                                 const float* __restrict__ B,
                                                 float* __restrict__ C, int M) {
    __shared__ float As[8][128];
    __shared__ float Bs[8][128];
    const int tid = threadIdx.x;
    const int m0 = blockIdx.x * 128;
    const int tr = (tid >> 4) * 4;     // 0..60
    const int tc = (tid & 15) * 4;     // 0..60
    const int lar = tid >> 1;          // 0..127 : A row within tile
    const int lak = (tid & 1) * 4;     // 0 or 4 : A k within tile
    const int lbr = tid >> 5;          // 0..7   : B k within tile
    const int lbc = (tid & 31) * 4;    // 0..124 : B col
    const int gmA = m0 + lar;

    float acc[2][2][4][4] = {};

    for (int k0 = 0; k0 < 128; k0 += 8) {
        float4 av = make_float4(0.f, 0.f, 0.f, 0.f);
        if (gmA < M) av = *(const float4*)(A + (size_t)gmA * 128 + k0 + lak);
        float4 bv = *(const float4*)(B + (size_t)(k0 + lbr) * 128 + lbc);
        __syncthreads();   // previous tile fully consumed
        As[lak + 0][lar] = av.x;
        As[lak + 1][lar] = av.y;
        As[lak + 2][lar] = av.z;
        As[lak + 3][lar] = av.w;
        *(float4*)&Bs[lbr][lbc] = bv;
        __syncthreads();
        #pragma unroll
        for (int k = 0; k < 8; ++k) {
            float4 a0 = *(const float4*)&As[k][tr];
            float4 a1 = *(const float4*)&As[k][tr + 64];
            float4 b0 = *(const float4*)&Bs[k][tc];
            float4 b1 = *(const float4*)&Bs[k][tc + 64];
            float ar[2][4] = {{a0.x, a0.y, a0.z, a0.w}, {a1.x, a1.y, a1.z, a1.w}};
            float br[2][4] = {{b0.x, b0.y, b0.z, b0.w}, {b1.x, b1.y, b1.z, b1.w}};
            #pragma unroll
            for (int ri = 0; ri < 2; ++ri)
                #pragma unroll
                for (int ci = 0; ci < 2; ++ci)
                    #pragma unroll
                    for (int r = 0; r < 4; ++r)
                        #pragma unroll
                        for (int c = 0; c < 4; ++c)
                            acc[ri][ci][r][c] = fmaf(ar[ri][r], br[ci][c], acc[ri][ci][r][c]);
        }
    }

    #pragma unroll
    for (int ri = 0; ri < 2; ++ri)
        #pragma unroll
        for (int r = 0; r < 4; ++r) {
            int gm = m0 + tr + ri * 64 + r;
            if (gm < M) {
                #pragma unroll
                for (int ci = 0; ci < 2; ++ci) {
                    float4 v = make_float4(acc[ri][ci][r][0], acc[ri][ci][r][1],
                                           acc[ri][ci][r][2], acc[ri][ci][r][3]);
                    *(float4*)(C + (size_t)gm * 128 + tc + ci * 64) = v;
                }
            }
        }
}

// ---------------- aggregation: one wave per node ----------------
// out[i,:] = relu( sum_{e: dst=i} h[src_e,:]*dinv[src_e]*dinv[i] + h[i,:]*dinv[i]^2 + b )

__global__ __launch_bounds__(256) void k_aggregate(const float* __restrict__ h,
                                                   const int* __restrict__ row_start,
                                                   const int* __restrict__ edge_src,
                                                   const float* __restrict__ edge_w,
                                                   const float* __restrict__ dinv,
                                                   const float* __restrict__ bias,
                                                   float* __restrict__ out, int n) {
    const int wave = (blockIdx.x * 256 + threadIdx.x) >> 6;
    const int lane = threadIdx.x & 63;
    if (wave >= n) return;
    const int i = wave;
    const float di = dinv[i];

    float2 hv = *(const float2*)(h + (size_t)i * 128 + lane * 2);
    float ax = hv.x * di * di;
    float ay = hv.y * di * di;

    const int s0 = row_start[i];
    const int s1 = row_start[i + 1];
    int j = s0;
    for (; j + 1 < s1; j += 2) {
        int sA = edge_src[j];
        int sB = edge_src[j + 1];
        float wA = edge_w[j] * di;
        float wB = edge_w[j + 1] * di;
        float2 vA = *(const float2*)(h + (size_t)sA * 128 + lane * 2);
        float2 vB = *(const float2*)(h + (size_t)sB * 128 + lane * 2);
        ax = fmaf(vA.x, wA, ax);  ay = fmaf(vA.y, wA, ay);
        ax = fmaf(vB.x, wB, ax);  ay = fmaf(vB.y, wB, ay);
    }
    if (j < s1) {
        int sA = edge_src[j];
        float wA = edge_w[j] * di;
        float2 vA = *(const float2*)(h + (size_t)sA * 128 + lane * 2);
        ax = fmaf(vA.x, wA, ax);  ay = fmaf(vA.y, wA, ay);
    }

    float2 bv = *(const float2*)(bias + lane * 2);
    float2 o;
    o.x = fmaxf(ax + bv.x, 0.f);
    o.y = fmaxf(ay + bv.y, 0.f);
    *(float2*)(out + (size_t)i * 128 + lane * 2) = o;
}

// ---------------- head GEMM: out[M x 16] = A[M x 128] * Wh[128 x 16] + bh ----------------

__global__ __launch_bounds__(256) void k_gemm_head(const float* __restrict__ A,
                                                   const float* __restrict__ Wh,
                                                   const float* __restrict__ bh,
                                                   float* __restrict__ C, int M) {
    __shared__ float Ws[128 * 16];
    const int t = threadIdx.x;
    #pragma unroll
    for (int j = 0; j < 2; ++j) {
        int idx = (t + j * 256) * 4;
        *(float4*)&Ws[idx] = *(const float4*)&Wh[idx];
    }
    __syncthreads();
    const int row = blockIdx.x * 256 + t;
    if (row >= M) return;

    float acc[16] = {};
    const float4* arow = (const float4*)(A + (size_t)row * 128);
    for (int k4 = 0; k4 < 32; ++k4) {
        float4 a = arow[k4];
        float av[4] = {a.x, a.y, a.z, a.w};
        #pragma unroll
        for (int j = 0; j < 4; ++j)
            #pragma unroll
            for (int c = 0; c < 16; ++c)
                acc[c] = fmaf(av[j], Ws[(k4 * 4 + j) * 16 + c], acc[c]);
    }
    #pragma unroll
    for (int c = 0; c < 16; ++c) acc[c] += bh[c];
    float* orow = C + (size_t)row * 16;
    #pragma unroll
    for (int c = 0; c < 16; c += 4)
        *(float4*)(orow + c) = make_float4(acc[c], acc[c + 1], acc[c + 2], acc[c + 3]);
}

// ---------------- launch ----------------

extern "C" void kernel_launch(void* const* d_in, const int* in_sizes, int n_in,
                              void* d_out, int out_size, void* d_ws, size_t ws_size,
                              hipStream_t stream) {
    const float* x  = (const float*)d_in[0];
    const float* W1 = (const float*)d_in[1];
    const float* b1 = (const float*)d_in[2];
    const float* W2 = (const float*)d_in[3];
    const float* b2 = (const float*)d_in[4];
    const float* Wh = (const float*)d_in[5];
    const float* bh = (const float*)d_in[6];
    const int*   ei = (const int*)d_in[7];

    const int N = in_sizes[0] / 128;
    const int E = in_sizes[7] / 2;
    const int* src = ei;
    const int* dst = ei + E;
    float* out = (float*)d_out;

    char* w = (char*)d_ws;
    auto alloc = [&](size_t bytes) -> void* {
        void* p = (void*)w;
        w += (bytes + 255) & ~(size_t)255;
        return p;
    };
    float* bufA      = (float*)alloc((size_t)N * 128 * sizeof(float));
    float* bufB      = (float*)alloc((size_t)N * 128 * sizeof(float));
    int*   indeg     = (int*)alloc((size_t)N * sizeof(int));
    int*   cursor    = (int*)alloc((size_t)N * sizeof(int));
    int*   row_start = (int*)alloc((size_t)(N + 1) * sizeof(int));
    float* dinv      = (float*)alloc((size_t)N * sizeof(float));
    int*   tilesums  = (int*)alloc(128 * sizeof(int));
    int*   edge_src  = (int*)alloc((size_t)E * sizeof(int));
    float* edge_w    = (float*)alloc((size_t)E * sizeof(float));

    // zero indeg + cursor (contiguous region)
    size_t zbytes = (size_t)((char*)cursor - (char*)indeg) + (size_t)N * sizeof(int);
    hipMemsetAsync(indeg, 0, zbytes, stream);

    // CSR build (graph identical for both layers)
    k_count<<<(E + 255) / 256, 256, 0, stream>>>(dst, indeg, E);
    const int nTiles = (N + 1023) / 1024;
    k_scan1<<<nTiles, 256, 0, stream>>>(indeg, row_start, tilesums, N);
    k_scan2<<<1, 128, 0, stream>>>(tilesums, nTiles);
    k_scan3_dinv<<<(N + 255) / 256, 256, 0, stream>>>(row_start, tilesums, indeg, dinv, N, E);
    k_fill<<<(E + 255) / 256, 256, 0, stream>>>(src, dst, dinv, row_start, cursor,
                                                edge_src, edge_w, E);

    const int gblocks = (N + 127) / 128;
    // layer 1
    k_gemm128<<<gblocks, 256, 0, stream>>>(x, W1, bufA, N);
    k_aggregate<<<(N + 3) / 4, 256, 0, stream>>>(bufA, row_start, edge_src, edge_w,
                                                 dinv, b1, bufB, N);
    // layer 2
    k_gemm128<<<gblocks, 256, 0, stream>>>(bufB, W2, bufA, N);
    k_aggregate<<<(N + 3) / 4, 256, 0, stream>>>(bufA, row_start, edge_src, edge_w,
                                                 dinv, b2, bufB, N);
    // head
    k_gemm_head<<<(N + 255) / 256, 256, 0, stream>>>(bufB, Wh, bh, out, N);
}

// Round 3
// 336.759 us; speedup vs baseline: 1.0861x; 1.0861x over previous
//
#include <hip/hip_runtime.h>
#include <hip/hip_bf16.h>

typedef short bf16x8 __attribute__((ext_vector_type(8)));
typedef float f32x4 __attribute__((ext_vector_type(4)));

// ---------- bf16 split helpers ----------
static __device__ __forceinline__ short f2bf(float f) {
    union { float f; unsigned u; } v; v.f = f;
    unsigned r = v.u + 0x7FFF + ((v.u >> 16) & 1);   // RNE
    return (short)(r >> 16);
}
static __device__ __forceinline__ float bf2f(short h) {
    union { unsigned u; float f; } v;
    v.u = ((unsigned)(unsigned short)h) << 16;
    return v.f;
}

// ---------------- CSR build ----------------

__global__ void k_count(const int* __restrict__ dst, int* __restrict__ indeg, int E) {
    int e = blockIdx.x * 256 + threadIdx.x;
    if (e < E) atomicAdd(&indeg[dst[e]], 1);
}

__global__ void k_scan1(const int* __restrict__ in, int* __restrict__ out,
                        int* __restrict__ sums, int n) {
    __shared__ int lds[256];
    const int t = threadIdx.x;
    const int base = blockIdx.x * 1024 + t * 4;
    int v0 = (base + 0 < n) ? in[base + 0] : 0;
    int v1 = (base + 1 < n) ? in[base + 1] : 0;
    int v2 = (base + 2 < n) ? in[base + 2] : 0;
    int v3 = (base + 3 < n) ? in[base + 3] : 0;
    const int tsum = v0 + v1 + v2 + v3;
    lds[t] = tsum;
    __syncthreads();
    #pragma unroll
    for (int off = 1; off < 256; off <<= 1) {
        int x = (t >= off) ? lds[t - off] : 0;
        __syncthreads();
        lds[t] += x;
        __syncthreads();
    }
    int excl = lds[t] - tsum;
    if (base + 0 < n) out[base + 0] = excl;  excl += v0;
    if (base + 1 < n) out[base + 1] = excl;  excl += v1;
    if (base + 2 < n) out[base + 2] = excl;  excl += v2;
    if (base + 3 < n) out[base + 3] = excl;
    if (t == 255) sums[blockIdx.x] = lds[255];
}

__global__ void k_scan2(int* __restrict__ sums, int nt) {
    __shared__ int lds[128];
    const int t = threadIdx.x;
    int v = (t < nt) ? sums[t] : 0;
    lds[t] = v;
    __syncthreads();
    #pragma unroll
    for (int off = 1; off < 128; off <<= 1) {
        int x = (t >= off) ? lds[t - off] : 0;
        __syncthreads();
        lds[t] += x;
        __syncthreads();
    }
    if (t < nt) sums[t] = lds[t] - v;
}

__global__ void k_scan3_dinv(int* __restrict__ row_start, const int* __restrict__ sums,
                             const int* __restrict__ indeg, float* __restrict__ dinv,
                             int n, int E) {
    int i = blockIdx.x * 256 + threadIdx.x;
    if (i < n) {
        row_start[i] += sums[i >> 10];
        dinv[i] = rsqrtf((float)indeg[i] + 1.0f);   // +1 self-loop
    }
    if (i == 0) row_start[n] = E;
}

__global__ void k_fill(const int* __restrict__ src, const int* __restrict__ dst,
                       const int* __restrict__ row_start, int* __restrict__ cursor,
                       int* __restrict__ edge_src, int E) {
    int e = blockIdx.x * 256 + threadIdx.x;
    if (e >= E) return;
    int s = src[e], d = dst[e];
    int pos = row_start[d] + atomicAdd(&cursor[d], 1);
    edge_src[pos] = s;
}

// ---------------- weight split: W[128][128] fp32 -> W^T hi/lo bf16 ----------------

__global__ void k_wsplit(const float* __restrict__ W, short* __restrict__ WT_hi,
                         short* __restrict__ WT_lo) {
    int idx = blockIdx.x * 256 + threadIdx.x;   // 16384
    int k = idx >> 7, n = idx & 127;
    float v = W[idx];
    short h = f2bf(v);
    short l = f2bf(v - bf2f(h));
    WT_hi[n * 128 + k] = h;
    WT_lo[n * 128 + k] = l;
}

// ---------------- MFMA GEMM: C[M x 128] = (A[M x 128] @ B) * dinv[row] ----------------
// No LDS. 4 waves/block: (m_sub 2) x (n_sub 2), each wave 64x64 via 4x4 frags of
// 16x16x32 bf16 MFMA. A split hi/lo on the fly in registers (3-term fp32 emulation).

__global__ __launch_bounds__(256) void k_gemm_mfma(const float* __restrict__ A,
                                                   const short* __restrict__ BT_hi,
                                                   const short* __restrict__ BT_lo,
                                                   const float* __restrict__ dinv,
                                                   float* __restrict__ C, int M) {
    const int tid  = threadIdx.x;
    const int wave = tid >> 6;
    const int lane = tid & 63;
    const int r16  = lane & 15;
    const int kg   = lane >> 4;              // k-group 0..3
    const int m0   = blockIdx.x * 128 + (wave >> 1) * 64;
    const int n0   = (wave & 1) * 64;

    f32x4 acc[4][4] = {};

    for (int kstep = 0; kstep < 4; ++kstep) {
        const int kb = kstep * 32 + kg * 8;

        // A fragments: 4 m-blocks, split hi/lo in regs
        bf16x8 ah[4], al[4];
        #pragma unroll
        for (int mi = 0; mi < 4; ++mi) {
            int row = m0 + mi * 16 + r16;
            if (row >= M) row = M - 1;
            const float* ap = A + (size_t)row * 128 + kb;
            float4 x0 = *(const float4*)ap;
            float4 x1 = *(const float4*)(ap + 4);
            float xs[8] = {x0.x, x0.y, x0.z, x0.w, x1.x, x1.y, x1.z, x1.w};
            #pragma unroll
            for (int j = 0; j < 8; ++j) {
                short h = f2bf(xs[j]);
                ah[mi][j] = h;
                al[mi][j] = f2bf(xs[j] - bf2f(h));
            }
        }
        // B fragments: 4 n-blocks (B^T pre-split, L1/L2 resident)
        bf16x8 bh[4], bl[4];
        #pragma unroll
        for (int ni = 0; ni < 4; ++ni) {
            int col = n0 + ni * 16 + r16;
            size_t idx = (size_t)col * 128 + kb;
            bh[ni] = *(const bf16x8*)(BT_hi + idx);
            bl[ni] = *(const bf16x8*)(BT_lo + idx);
        }
        #pragma unroll
        for (int mi = 0; mi < 4; ++mi)
            #pragma unroll
            for (int ni = 0; ni < 4; ++ni) {
                acc[mi][ni] = __builtin_amdgcn_mfma_f32_16x16x32_bf16(al[mi], bh[ni], acc[mi][ni], 0, 0, 0);
                acc[mi][ni] = __builtin_amdgcn_mfma_f32_16x16x32_bf16(ah[mi], bl[ni], acc[mi][ni], 0, 0, 0);
                acc[mi][ni] = __builtin_amdgcn_mfma_f32_16x16x32_bf16(ah[mi], bh[ni], acc[mi][ni], 0, 0, 0);
            }
    }

    // epilogue: D layout col=lane&15, row=(lane>>4)*4+reg ; scale by dinv[row]
    #pragma unroll
    for (int mi = 0; mi < 4; ++mi) {
        #pragma unroll
        for (int r = 0; r < 4; ++r) {
            int row = m0 + mi * 16 + (lane >> 4) * 4 + r;
            if (row < M) {
                float dr = dinv[row];
                #pragma unroll
                for (int ni = 0; ni < 4; ++ni) {
                    int col = n0 + ni * 16 + r16;
                    C[(size_t)row * 128 + col] = acc[mi][ni][r] * dr;
                }
            }
        }
    }
}

// ---------------- aggregation: 2 nodes per wave, 32 lanes x float4 ----------------
// out[i,:] = relu( dinv[i] * ( h'[i,:] + sum_{e: dst=i} h'[src_e,:] ) + b )
// where h' = h * dinv was produced by the GEMM epilogue.

__global__ __launch_bounds__(256) void k_aggregate(const float* __restrict__ hp,
                                                   const int* __restrict__ row_start,
                                                   const int* __restrict__ edge_src,
                                                   const float* __restrict__ dinv,
                                                   const float* __restrict__ bias,
                                                   float* __restrict__ out, int n) {
    const int wave = (blockIdx.x * 256 + threadIdx.x) >> 6;
    const int half = (threadIdx.x >> 5) & 1;
    const int l32  = threadIdx.x & 31;
    const int i    = wave * 2 + half;
    if (i >= n) return;

    const float4* __restrict__ h4 = (const float4*)hp;
    float4 a0 = h4[(size_t)i * 32 + l32];    // self term h'[i]
    float4 a1 = make_float4(0.f, 0.f, 0.f, 0.f);

    int j = row_start[i];
    const int e = row_start[i + 1];
    for (; j + 3 < e; j += 4) {
        int s0 = edge_src[j], s1 = edge_src[j + 1];
        int s2 = edge_src[j + 2], s3 = edge_src[j + 3];
        float4 v0 = h4[(size_t)s0 * 32 + l32];
        float4 v1 = h4[(size_t)s1 * 32 + l32];
        float4 v2 = h4[(size_t)s2 * 32 + l32];
        float4 v3 = h4[(size_t)s3 * 32 + l32];
        a0.x += v0.x; a0.y += v0.y; a0.z += v0.z; a0.w += v0.w;
        a1.x += v1.x; a1.y += v1.y; a1.z += v1.z; a1.w += v1.w;
        a0.x += v2.x; a0.y += v2.y; a0.z += v2.z; a0.w += v2.w;
        a1.x += v3.x; a1.y += v3.y; a1.z += v3.z; a1.w += v3.w;
    }
    for (; j < e; ++j) {
        int s0 = edge_src[j];
        float4 v0 = h4[(size_t)s0 * 32 + l32];
        a0.x += v0.x; a0.y += v0.y; a0.z += v0.z; a0.w += v0.w;
    }

    const float di = dinv[i];
    float4 b = ((const float4*)bias)[l32];
    float4 o;
    o.x = fmaxf(fmaf(a0.x + a1.x, di, b.x), 0.f);
    o.y = fmaxf(fmaf(a0.y + a1.y, di, b.y), 0.f);
    o.z = fmaxf(fmaf(a0.z + a1.z, di, b.z), 0.f);
    o.w = fmaxf(fmaf(a0.w + a1.w, di, b.w), 0.f);
    ((float4*)out)[(size_t)i * 32 + l32] = o;
}

// ---------------- head GEMM: out[M x 16] = A[M x 128] * Wh[128 x 16] + bh ----------------
// One wave per 16 rows; K split across 4 lane-groups; shfl reduce.

__global__ __launch_bounds__(256) void k_gemm_head(const float* __restrict__ A,
                                                   const float* __restrict__ Wh,
                                                   const float* __restrict__ bh,
                                                   float* __restrict__ C, int M) {
    __shared__ float Ws[128 * 16];
    const int t = threadIdx.x;
    *(float4*)&Ws[t * 8]     = *(const float4*)&Wh[t * 8];
    *(float4*)&Ws[t * 8 + 4] = *(const float4*)&Wh[t * 8 + 4];
    __syncthreads();

    const int wave = t >> 6;
    const int lane = t & 63;
    const int r    = lane & 15;
    const int kq   = lane >> 4;
    int row = (blockIdx.x * 4 + wave) * 16 + r;
    int lrow = (row < M) ? row : (M - 1);

    const float4* ap = (const float4*)(A + (size_t)lrow * 128 + kq * 32);
    float acc[16] = {};
    #pragma unroll
    for (int k4 = 0; k4 < 8; ++k4) {
        float4 a = ap[k4];
        float av[4] = {a.x, a.y, a.z, a.w};
        #pragma unroll
        for (int j = 0; j < 4; ++j) {
            int k = kq * 32 + k4 * 4 + j;
            #pragma unroll
            for (int c = 0; c < 16; ++c)
                acc[c] = fmaf(av[j], Ws[k * 16 + c], acc[c]);
        }
    }
    #pragma unroll
    for (int c = 0; c < 16; ++c) {
        acc[c] += __shfl_down(acc[c], 16);
        acc[c] += __shfl_down(acc[c], 32);
    }
    if (lane < 16 && row < M) {
        float* orow = C + (size_t)row * 16;
        #pragma unroll
        for (int c = 0; c < 16; c += 4) {
            float4 v = make_float4(acc[c] + bh[c], acc[c + 1] + bh[c + 1],
                                   acc[c + 2] + bh[c + 2], acc[c + 3] + bh[c + 3]);
            *(float4*)(orow + c) = v;
        }
    }
}

// ---------------- launch ----------------

extern "C" void kernel_launch(void* const* d_in, const int* in_sizes, int n_in,
                              void* d_out, int out_size, void* d_ws, size_t ws_size,
                              hipStream_t stream) {
    const float* x  = (const float*)d_in[0];
    const float* W1 = (const float*)d_in[1];
    const float* b1 = (const float*)d_in[2];
    const float* W2 = (const float*)d_in[3];
    const float* b2 = (const float*)d_in[4];
    const float* Wh = (const float*)d_in[5];
    const float* bh = (const float*)d_in[6];
    const int*   ei = (const int*)d_in[7];

    const int N = in_sizes[0] / 128;
    const int E = in_sizes[7] / 2;
    const int* src = ei;
    const int* dst = ei + E;
    float* out = (float*)d_out;

    char* w = (char*)d_ws;
    auto alloc = [&](size_t bytes) -> void* {
        void* p = (void*)w;
        w += (bytes + 255) & ~(size_t)255;
        return p;
    };
    float* bufA      = (float*)alloc((size_t)N * 128 * sizeof(float));
    float* bufB      = (float*)alloc((size_t)N * 128 * sizeof(float));
    int*   indeg     = (int*)alloc((size_t)N * sizeof(int));
    int*   cursor    = (int*)alloc((size_t)N * sizeof(int));
    int*   row_start = (int*)alloc((size_t)(N + 1) * sizeof(int));
    float* dinv      = (float*)alloc((size_t)N * sizeof(float));
    int*   tilesums  = (int*)alloc(128 * sizeof(int));
    int*   edge_src  = (int*)alloc((size_t)E * sizeof(int));
    short* w1hiT     = (short*)alloc(128 * 128 * sizeof(short));
    short* w1loT     = (short*)alloc(128 * 128 * sizeof(short));
    short* w2hiT     = (short*)alloc(128 * 128 * sizeof(short));
    short* w2loT     = (short*)alloc(128 * 128 * sizeof(short));

    // zero indeg + cursor (contiguous region)
    size_t zbytes = (size_t)((char*)cursor - (char*)indeg) + (size_t)N * sizeof(int);
    hipMemsetAsync(indeg, 0, zbytes, stream);

    // CSR build (graph identical for both layers)
    k_count<<<(E + 255) / 256, 256, 0, stream>>>(dst, indeg, E);
    const int nTiles = (N + 1023) / 1024;
    k_scan1<<<nTiles, 256, 0, stream>>>(indeg, row_start, tilesums, N);
    k_scan2<<<1, 128, 0, stream>>>(tilesums, nTiles);
    k_scan3_dinv<<<(N + 255) / 256, 256, 0, stream>>>(row_start, tilesums, indeg, dinv, N, E);
    k_fill<<<(E + 255) / 256, 256, 0, stream>>>(src, dst, row_start, cursor, edge_src, E);

    // weight splits (transposed bf16 hi/lo)
    k_wsplit<<<64, 256, 0, stream>>>(W1, w1hiT, w1loT);
    k_wsplit<<<64, 256, 0, stream>>>(W2, w2hiT, w2loT);

    const int gblocks = (N + 127) / 128;
    // layer 1
    k_gemm_mfma<<<gblocks, 256, 0, stream>>>(x, w1hiT, w1loT, dinv, bufA, N);
    k_aggregate<<<(N + 7) / 8, 256, 0, stream>>>(bufA, row_start, edge_src, dinv, b1, bufB, N);
    // layer 2
    k_gemm_mfma<<<gblocks, 256, 0, stream>>>(bufB, w2hiT, w2loT, dinv, bufA, N);
    k_aggregate<<<(N + 7) / 8, 256, 0, stream>>>(bufA, row_start, edge_src, dinv, b2, bufB, N);
    // head
    k_gemm_head<<<(N + 63) / 64, 256, 0, stream>>>(bufB, Wh, bh, out, N);
}

// Round 4
// 285.434 us; speedup vs baseline: 1.2814x; 1.1798x over previous
//
#include <hip/hip_runtime.h>
#include <hip/hip_bf16.h>

typedef short bf16x8 __attribute__((ext_vector_type(8)));
typedef float f32x4 __attribute__((ext_vector_type(4)));

// ---------- bf16 helpers ----------
static __device__ __forceinline__ short f2bf(float f) {
    union { float f; unsigned u; } v; v.f = f;
    unsigned r = v.u + 0x7FFF + ((v.u >> 16) & 1);   // RNE
    return (short)(r >> 16);
}
static __device__ __forceinline__ float bf2f(short h) {
    union { unsigned u; float f; } v;
    v.u = ((unsigned)(unsigned short)h) << 16;
    return v.f;
}
static __device__ __forceinline__ float bfu2f(unsigned short h) {
    union { unsigned u; float f; } v;
    v.u = ((unsigned)h) << 16;
    return v.f;
}

// ---------------- CSR build ----------------

__global__ void k_count(const int* __restrict__ dst, int* __restrict__ indeg, int E) {
    int e = blockIdx.x * 256 + threadIdx.x;
    if (e < E) atomicAdd(&indeg[dst[e]], 1);
}

__global__ void k_scan1(const int* __restrict__ in, int* __restrict__ out,
                        int* __restrict__ sums, int n) {
    __shared__ int lds[256];
    const int t = threadIdx.x;
    const int base = blockIdx.x * 1024 + t * 4;
    int v0 = (base + 0 < n) ? in[base + 0] : 0;
    int v1 = (base + 1 < n) ? in[base + 1] : 0;
    int v2 = (base + 2 < n) ? in[base + 2] : 0;
    int v3 = (base + 3 < n) ? in[base + 3] : 0;
    const int tsum = v0 + v1 + v2 + v3;
    lds[t] = tsum;
    __syncthreads();
    #pragma unroll
    for (int off = 1; off < 256; off <<= 1) {
        int x = (t >= off) ? lds[t - off] : 0;
        __syncthreads();
        lds[t] += x;
        __syncthreads();
    }
    int excl = lds[t] - tsum;
    if (base + 0 < n) out[base + 0] = excl;  excl += v0;
    if (base + 1 < n) out[base + 1] = excl;  excl += v1;
    if (base + 2 < n) out[base + 2] = excl;  excl += v2;
    if (base + 3 < n) out[base + 3] = excl;
    if (t == 255) sums[blockIdx.x] = lds[255];
}

__global__ void k_scan2(int* __restrict__ sums, int nt) {
    __shared__ int lds[128];
    const int t = threadIdx.x;
    int v = (t < nt) ? sums[t] : 0;
    lds[t] = v;
    __syncthreads();
    #pragma unroll
    for (int off = 1; off < 128; off <<= 1) {
        int x = (t >= off) ? lds[t - off] : 0;
        __syncthreads();
        lds[t] += x;
        __syncthreads();
    }
    if (t < nt) sums[t] = lds[t] - v;
}

__global__ void k_scan3_dinv(int* __restrict__ row_start, const int* __restrict__ sums,
                             const int* __restrict__ indeg, float* __restrict__ dinv,
                             int n, int E) {
    int i = blockIdx.x * 256 + threadIdx.x;
    if (i < n) {
        row_start[i] += sums[i >> 10];
        dinv[i] = rsqrtf((float)indeg[i] + 1.0f);   // +1 self-loop
    }
    if (i == 0) row_start[n] = E;
}

__global__ void k_fill(const int* __restrict__ src, const int* __restrict__ dst,
                       const int* __restrict__ row_start, int* __restrict__ cursor,
                       int* __restrict__ edge_src, int E) {
    int e = blockIdx.x * 256 + threadIdx.x;
    if (e >= E) return;
    int s = src[e], d = dst[e];
    int pos = row_start[d] + atomicAdd(&cursor[d], 1);
    edge_src[pos] = s;
}

// ---------------- weight split: W[128][128] fp32 -> W^T hi/lo bf16 ----------------

__global__ void k_wsplit(const float* __restrict__ W, short* __restrict__ WT_hi,
                         short* __restrict__ WT_lo) {
    int idx = blockIdx.x * 256 + threadIdx.x;   // 16384
    int k = idx >> 7, n = idx & 127;
    float v = W[idx];
    short h = f2bf(v);
    short l = f2bf(v - bf2f(h));
    WT_hi[n * 128 + k] = h;
    WT_lo[n * 128 + k] = l;
}

// ---------------- activation split: X[total] fp32 -> hi/lo bf16 planes ----------------

__global__ void k_xsplit(const float* __restrict__ X, unsigned short* __restrict__ Xhi,
                         unsigned short* __restrict__ Xlo, int total4) {
    int idx = blockIdx.x * 256 + threadIdx.x;   // one float4 per thread
    if (idx >= total4) return;
    float4 v = ((const float4*)X)[idx];
    ushort4 h, l;
    h.x = (unsigned short)f2bf(v.x);  l.x = (unsigned short)f2bf(v.x - bfu2f(h.x));
    h.y = (unsigned short)f2bf(v.y);  l.y = (unsigned short)f2bf(v.y - bfu2f(h.y));
    h.z = (unsigned short)f2bf(v.z);  l.z = (unsigned short)f2bf(v.z - bfu2f(h.z));
    h.w = (unsigned short)f2bf(v.w);  l.w = (unsigned short)f2bf(v.w - bfu2f(h.w));
    ((ushort4*)Xhi)[idx] = h;
    ((ushort4*)Xlo)[idx] = l;
}

// ---------------- MFMA GEMM: Cbf[M x 128] = bf16( (A @ B) * dinv[row] ) ----------------
// A pre-split into hi/lo bf16 planes (pure loads). 3-term fp32 emulation.
// 4 waves/block: (m_sub 2) x (n_sub 2), each wave 64x64 via 4x4 frags of 16x16x32.

__global__ __launch_bounds__(256) void k_gemm_mfma(const unsigned short* __restrict__ Ahi,
                                                   const unsigned short* __restrict__ Alo,
                                                   const short* __restrict__ BT_hi,
                                                   const short* __restrict__ BT_lo,
                                                   const float* __restrict__ dinv,
                                                   unsigned short* __restrict__ Cbf, int M) {
    const int tid  = threadIdx.x;
    const int wave = tid >> 6;
    const int lane = tid & 63;
    const int r16  = lane & 15;
    const int kg   = lane >> 4;              // k-group 0..3
    const int m0   = blockIdx.x * 128 + (wave >> 1) * 64;
    const int n0   = (wave & 1) * 64;

    f32x4 acc[4][4] = {};

    for (int kstep = 0; kstep < 4; ++kstep) {
        const int kb = kstep * 32 + kg * 8;

        bf16x8 ah[4], al[4];
        #pragma unroll
        for (int mi = 0; mi < 4; ++mi) {
            int row = m0 + mi * 16 + r16;
            if (row >= M) row = M - 1;
            size_t off = (size_t)row * 128 + kb;
            ah[mi] = *(const bf16x8*)(Ahi + off);
            al[mi] = *(const bf16x8*)(Alo + off);
        }
        bf16x8 bh[4], bl[4];
        #pragma unroll
        for (int ni = 0; ni < 4; ++ni) {
            int col = n0 + ni * 16 + r16;
            size_t idx = (size_t)col * 128 + kb;
            bh[ni] = *(const bf16x8*)(BT_hi + idx);
            bl[ni] = *(const bf16x8*)(BT_lo + idx);
        }
        #pragma unroll
        for (int mi = 0; mi < 4; ++mi)
            #pragma unroll
            for (int ni = 0; ni < 4; ++ni) {
                acc[mi][ni] = __builtin_amdgcn_mfma_f32_16x16x32_bf16(al[mi], bh[ni], acc[mi][ni], 0, 0, 0);
                acc[mi][ni] = __builtin_amdgcn_mfma_f32_16x16x32_bf16(ah[mi], bl[ni], acc[mi][ni], 0, 0, 0);
                acc[mi][ni] = __builtin_amdgcn_mfma_f32_16x16x32_bf16(ah[mi], bh[ni], acc[mi][ni], 0, 0, 0);
            }
    }

    // epilogue: D layout col=lane&15, row=(lane>>4)*4+reg ; scale by dinv[row], cast bf16
    #pragma unroll
    for (int mi = 0; mi < 4; ++mi) {
        #pragma unroll
        for (int r = 0; r < 4; ++r) {
            int row = m0 + mi * 16 + (lane >> 4) * 4 + r;
            if (row < M) {
                float dr = dinv[row];
                #pragma unroll
                for (int ni = 0; ni < 4; ++ni) {
                    int col = n0 + ni * 16 + r16;
                    Cbf[(size_t)row * 128 + col] = (unsigned short)f2bf(acc[mi][ni][r] * dr);
                }
            }
        }
    }
}

// ---------------- aggregation: 2 nodes/wave, 32 lanes x bf16x4, masked 4-wide unroll ----
// out[i,:] = relu( dinv[i] * ( h'[i,:] + sum_{e: dst=i} h'[src_e,:] ) + b )
// MODE 0: write hi/lo bf16 planes (feeds next MFMA GEMM)
// MODE 1: write fp32 (feeds head GEMM)

template <int MODE>
__global__ __launch_bounds__(256) void k_aggregate(const unsigned short* __restrict__ hp,
                                                   const int* __restrict__ row_start,
                                                   const int* __restrict__ edge_src,
                                                   const float* __restrict__ dinv,
                                                   const float* __restrict__ bias,
                                                   unsigned short* __restrict__ outHi,
                                                   unsigned short* __restrict__ outLo,
                                                   float* __restrict__ outF, int n) {
    const int wave = (blockIdx.x * 256 + threadIdx.x) >> 6;
    const int half = (threadIdx.x >> 5) & 1;
    const int l32  = threadIdx.x & 31;
    const int i    = wave * 2 + half;
    if (i >= n) return;

    const ushort4* __restrict__ h4 = (const ushort4*)hp;   // 32 x ushort4 per row

    ushort4 sv = h4[(size_t)i * 32 + l32];                 // self term
    float a0 = bfu2f(sv.x), a1 = bfu2f(sv.y), a2 = bfu2f(sv.z), a3 = bfu2f(sv.w);
    float b0 = 0.f, b1 = 0.f, b2 = 0.f, b3 = 0.f;

    int j = row_start[i];
    const int e = row_start[i + 1];
    while (j < e) {
        const int e1 = e - 1;
        int j1 = j + 1, j2 = j + 2, j3 = j + 3;
        bool c1 = j1 < e, c2 = j2 < e, c3 = j3 < e;
        int s0i = edge_src[j];
        int s1i = edge_src[c1 ? j1 : e1];
        int s2i = edge_src[c2 ? j2 : e1];
        int s3i = edge_src[c3 ? j3 : e1];
        ushort4 v0 = h4[(size_t)s0i * 32 + l32];
        ushort4 v1 = h4[(size_t)s1i * 32 + l32];
        ushort4 v2 = h4[(size_t)s2i * 32 + l32];
        ushort4 v3 = h4[(size_t)s3i * 32 + l32];
        float m1 = c1 ? 1.f : 0.f, m2 = c2 ? 1.f : 0.f, m3 = c3 ? 1.f : 0.f;
        a0 += bfu2f(v0.x); a1 += bfu2f(v0.y); a2 += bfu2f(v0.z); a3 += bfu2f(v0.w);
        b0 = fmaf(bfu2f(v1.x), m1, b0); b1 = fmaf(bfu2f(v1.y), m1, b1);
        b2 = fmaf(bfu2f(v1.z), m1, b2); b3 = fmaf(bfu2f(v1.w), m1, b3);
        a0 = fmaf(bfu2f(v2.x), m2, a0); a1 = fmaf(bfu2f(v2.y), m2, a1);
        a2 = fmaf(bfu2f(v2.z), m2, a2); a3 = fmaf(bfu2f(v2.w), m2, a3);
        b0 = fmaf(bfu2f(v3.x), m3, b0); b1 = fmaf(bfu2f(v3.y), m3, b1);
        b2 = fmaf(bfu2f(v3.z), m3, b2); b3 = fmaf(bfu2f(v3.w), m3, b3);
        j += 4;
    }

    const float di = dinv[i];
    float4 bsv = ((const float4*)bias)[l32];
    float r0 = fmaxf(fmaf(a0 + b0, di, bsv.x), 0.f);
    float r1 = fmaxf(fmaf(a1 + b1, di, bsv.y), 0.f);
    float r2 = fmaxf(fmaf(a2 + b2, di, bsv.z), 0.f);
    float r3 = fmaxf(fmaf(a3 + b3, di, bsv.w), 0.f);

    if (MODE == 0) {
        ushort4 hi, lo;
        hi.x = (unsigned short)f2bf(r0);  lo.x = (unsigned short)f2bf(r0 - bfu2f(hi.x));
        hi.y = (unsigned short)f2bf(r1);  lo.y = (unsigned short)f2bf(r1 - bfu2f(hi.y));
        hi.z = (unsigned short)f2bf(r2);  lo.z = (unsigned short)f2bf(r2 - bfu2f(hi.z));
        hi.w = (unsigned short)f2bf(r3);  lo.w = (unsigned short)f2bf(r3 - bfu2f(hi.w));
        ((ushort4*)outHi)[(size_t)i * 32 + l32] = hi;
        ((ushort4*)outLo)[(size_t)i * 32 + l32] = lo;
    } else {
        ((float4*)outF)[(size_t)i * 32 + l32] = make_float4(r0, r1, r2, r3);
    }
}

// ---------------- head GEMM: out[M x 16] = A[M x 128] * Wh[128 x 16] + bh ----------------

__global__ __launch_bounds__(256) void k_gemm_head(const float* __restrict__ A,
                                                   const float* __restrict__ Wh,
                                                   const float* __restrict__ bh,
                                                   float* __restrict__ C, int M) {
    __shared__ float Ws[128 * 16];
    const int t = threadIdx.x;
    *(float4*)&Ws[t * 8]     = *(const float4*)&Wh[t * 8];
    *(float4*)&Ws[t * 8 + 4] = *(const float4*)&Wh[t * 8 + 4];
    __syncthreads();

    const int wave = t >> 6;
    const int lane = t & 63;
    const int r    = lane & 15;
    const int kq   = lane >> 4;
    int row = (blockIdx.x * 4 + wave) * 16 + r;
    int lrow = (row < M) ? row : (M - 1);

    const float4* ap = (const float4*)(A + (size_t)lrow * 128 + kq * 32);
    float acc[16] = {};
    #pragma unroll
    for (int k4 = 0; k4 < 8; ++k4) {
        float4 a = ap[k4];
        float av[4] = {a.x, a.y, a.z, a.w};
        #pragma unroll
        for (int j = 0; j < 4; ++j) {
            int k = kq * 32 + k4 * 4 + j;
            #pragma unroll
            for (int c = 0; c < 16; ++c)
                acc[c] = fmaf(av[j], Ws[k * 16 + c], acc[c]);
        }
    }
    #pragma unroll
    for (int c = 0; c < 16; ++c) {
        acc[c] += __shfl_down(acc[c], 16);
        acc[c] += __shfl_down(acc[c], 32);
    }
    if (lane < 16 && row < M) {
        float* orow = C + (size_t)row * 16;
        #pragma unroll
        for (int c = 0; c < 16; c += 4) {
            float4 v = make_float4(acc[c] + bh[c], acc[c + 1] + bh[c + 1],
                                   acc[c + 2] + bh[c + 2], acc[c + 3] + bh[c + 3]);
            *(float4*)(orow + c) = v;
        }
    }
}

// ---------------- launch ----------------

extern "C" void kernel_launch(void* const* d_in, const int* in_sizes, int n_in,
                              void* d_out, int out_size, void* d_ws, size_t ws_size,
                              hipStream_t stream) {
    const float* x  = (const float*)d_in[0];
    const float* W1 = (const float*)d_in[1];
    const float* b1 = (const float*)d_in[2];
    const float* W2 = (const float*)d_in[3];
    const float* b2 = (const float*)d_in[4];
    const float* Wh = (const float*)d_in[5];
    const float* bh = (const float*)d_in[6];
    const int*   ei = (const int*)d_in[7];

    const int N = in_sizes[0] / 128;
    const int E = in_sizes[7] / 2;
    const int* src = ei;
    const int* dst = ei + E;
    float* out = (float*)d_out;

    char* w = (char*)d_ws;
    auto alloc = [&](size_t bytes) -> void* {
        void* p = (void*)w;
        w += (bytes + 255) & ~(size_t)255;
        return p;
    };
    float*          bufF      = (float*)alloc((size_t)N * 128 * sizeof(float));
    unsigned short* planeHi   = (unsigned short*)alloc((size_t)N * 128 * sizeof(short));
    unsigned short* planeLo   = (unsigned short*)alloc((size_t)N * 128 * sizeof(short));
    unsigned short* hp        = (unsigned short*)alloc((size_t)N * 128 * sizeof(short));
    int*   indeg     = (int*)alloc((size_t)N * sizeof(int));
    int*   cursor    = (int*)alloc((size_t)N * sizeof(int));
    int*   row_start = (int*)alloc((size_t)(N + 1) * sizeof(int));
    float* dinv      = (float*)alloc((size_t)N * sizeof(float));
    int*   tilesums  = (int*)alloc(128 * sizeof(int));
    int*   edge_src  = (int*)alloc((size_t)E * sizeof(int));
    short* w1hiT     = (short*)alloc(128 * 128 * sizeof(short));
    short* w1loT     = (short*)alloc(128 * 128 * sizeof(short));
    short* w2hiT     = (short*)alloc(128 * 128 * sizeof(short));
    short* w2loT     = (short*)alloc(128 * 128 * sizeof(short));

    // zero indeg + cursor (contiguous region)
    size_t zbytes = (size_t)((char*)cursor - (char*)indeg) + (size_t)N * sizeof(int);
    hipMemsetAsync(indeg, 0, zbytes, stream);

    // CSR build (graph identical for both layers)
    k_count<<<(E + 255) / 256, 256, 0, stream>>>(dst, indeg, E);
    const int nTiles = (N + 1023) / 1024;
    k_scan1<<<nTiles, 256, 0, stream>>>(indeg, row_start, tilesums, N);
    k_scan2<<<1, 128, 0, stream>>>(tilesums, nTiles);
    k_scan3_dinv<<<(N + 255) / 256, 256, 0, stream>>>(row_start, tilesums, indeg, dinv, N, E);
    k_fill<<<(E + 255) / 256, 256, 0, stream>>>(src, dst, row_start, cursor, edge_src, E);

    // weight + activation splits
    k_wsplit<<<64, 256, 0, stream>>>(W1, w1hiT, w1loT);
    k_wsplit<<<64, 256, 0, stream>>>(W2, w2hiT, w2loT);
    const int total4 = N * 32;   // N*128/4
    k_xsplit<<<(total4 + 255) / 256, 256, 0, stream>>>(x, planeHi, planeLo, total4);

    const int gblocks = (N + 127) / 128;
    const int ablocks = (N + 7) / 8;
    // layer 1
    k_gemm_mfma<<<gblocks, 256, 0, stream>>>(planeHi, planeLo, w1hiT, w1loT, dinv, hp, N);
    k_aggregate<0><<<ablocks, 256, 0, stream>>>(hp, row_start, edge_src, dinv, b1,
                                                planeHi, planeLo, nullptr, N);
    // layer 2
    k_gemm_mfma<<<gblocks, 256, 0, stream>>>(planeHi, planeLo, w2hiT, w2loT, dinv, hp, N);
    k_aggregate<1><<<ablocks, 256, 0, stream>>>(hp, row_start, edge_src, dinv, b2,
                                                nullptr, nullptr, bufF, N);
    // head
    k_gemm_head<<<(N + 63) / 64, 256, 0, stream>>>(bufF, Wh, bh, out, N);
}

// Round 5
// 251.099 us; speedup vs baseline: 1.4567x; 1.1367x over previous
//
#include <hip/hip_runtime.h>
#include <hip/hip_bf16.h>

typedef short bf16x8 __attribute__((ext_vector_type(8)));
typedef unsigned short u16x8 __attribute__((ext_vector_type(8)));
typedef float f32x4 __attribute__((ext_vector_type(4)));

// ---------- bf16 helpers ----------
static __device__ __forceinline__ short f2bf(float f) {
    union { float f; unsigned u; } v; v.f = f;
    unsigned r = v.u + 0x7FFF + ((v.u >> 16) & 1);   // RNE
    return (short)(r >> 16);
}
static __device__ __forceinline__ float bf2f(short h) {
    union { unsigned u; float f; } v;
    v.u = ((unsigned)(unsigned short)h) << 16;
    return v.f;
}
static __device__ __forceinline__ float bfu2f(unsigned short h) {
    union { unsigned u; float f; } v;
    v.u = ((unsigned)h) << 16;
    return v.f;
}

// ---------------- CSR build ----------------
// Pass 1: histogram; the atomic's return value IS the edge's rank within its
// destination bucket (stored coalesced). Pass 3 (fill) then needs no atomic.

__global__ void k_count_rank(const int* __restrict__ dst, int* __restrict__ indeg,
                             int* __restrict__ rank, int E) {
    int e = blockIdx.x * 256 + threadIdx.x;
    if (e < E) rank[e] = atomicAdd(&indeg[dst[e]], 1);
}

__global__ void k_scan1(const int* __restrict__ in, int* __restrict__ out,
                        int* __restrict__ sums, int n) {
    __shared__ int lds[256];
    const int t = threadIdx.x;
    const int base = blockIdx.x * 1024 + t * 4;
    int v0 = (base + 0 < n) ? in[base + 0] : 0;
    int v1 = (base + 1 < n) ? in[base + 1] : 0;
    int v2 = (base + 2 < n) ? in[base + 2] : 0;
    int v3 = (base + 3 < n) ? in[base + 3] : 0;
    const int tsum = v0 + v1 + v2 + v3;
    lds[t] = tsum;
    __syncthreads();
    #pragma unroll
    for (int off = 1; off < 256; off <<= 1) {
        int x = (t >= off) ? lds[t - off] : 0;
        __syncthreads();
        lds[t] += x;
        __syncthreads();
    }
    int excl = lds[t] - tsum;
    if (base + 0 < n) out[base + 0] = excl;  excl += v0;
    if (base + 1 < n) out[base + 1] = excl;  excl += v1;
    if (base + 2 < n) out[base + 2] = excl;  excl += v2;
    if (base + 3 < n) out[base + 3] = excl;
    if (t == 255) sums[blockIdx.x] = lds[255];
}

__global__ void k_scan2(int* __restrict__ sums, int nt) {
    __shared__ int lds[128];
    const int t = threadIdx.x;
    int v = (t < nt) ? sums[t] : 0;
    lds[t] = v;
    __syncthreads();
    #pragma unroll
    for (int off = 1; off < 128; off <<= 1) {
        int x = (t >= off) ? lds[t - off] : 0;
        __syncthreads();
        lds[t] += x;
        __syncthreads();
    }
    if (t < nt) sums[t] = lds[t] - v;
}

__global__ void k_scan3_dinv(int* __restrict__ row_start, const int* __restrict__ sums,
                             const int* __restrict__ indeg, float* __restrict__ dinv,
                             int n, int E) {
    int i = blockIdx.x * 256 + threadIdx.x;
    if (i < n) {
        row_start[i] += sums[i >> 10];
        dinv[i] = rsqrtf((float)indeg[i] + 1.0f);   // +1 self-loop
    }
    if (i == 0) row_start[n] = E;
}

__global__ void k_fill_rank(const int* __restrict__ src, const int* __restrict__ dst,
                            const int* __restrict__ rank, const int* __restrict__ row_start,
                            int* __restrict__ edge_src, int E) {
    int e = blockIdx.x * 256 + threadIdx.x;
    if (e >= E) return;
    edge_src[row_start[dst[e]] + rank[e]] = src[e];
}

// ---------------- weight split: W[128][128] fp32 -> W^T hi/lo bf16 ----------------

__global__ void k_wsplit(const float* __restrict__ W, short* __restrict__ WT_hi,
                         short* __restrict__ WT_lo) {
    int idx = blockIdx.x * 256 + threadIdx.x;   // 16384
    int k = idx >> 7, n = idx & 127;
    float v = W[idx];
    short h = f2bf(v);
    short l = f2bf(v - bf2f(h));
    WT_hi[n * 128 + k] = h;
    WT_lo[n * 128 + k] = l;
}

// ---------------- activation split: X[total] fp32 -> hi/lo bf16 planes ----------------

__global__ void k_xsplit(const float* __restrict__ X, unsigned short* __restrict__ Xhi,
                         unsigned short* __restrict__ Xlo, int total4) {
    int idx = blockIdx.x * 256 + threadIdx.x;   // one float4 per thread
    if (idx >= total4) return;
    float4 v = ((const float4*)X)[idx];
    ushort4 h, l;
    h.x = (unsigned short)f2bf(v.x);  l.x = (unsigned short)f2bf(v.x - bfu2f(h.x));
    h.y = (unsigned short)f2bf(v.y);  l.y = (unsigned short)f2bf(v.y - bfu2f(h.y));
    h.z = (unsigned short)f2bf(v.z);  l.z = (unsigned short)f2bf(v.z - bfu2f(h.z));
    h.w = (unsigned short)f2bf(v.w);  l.w = (unsigned short)f2bf(v.w - bfu2f(h.w));
    ((ushort4*)Xhi)[idx] = h;
    ((ushort4*)Xlo)[idx] = l;
}

// ---------------- MFMA GEMM: Cbf[M x 128] = bf16( (A @ B) * dinv[row] ) ----------------
// A pre-split into hi/lo bf16 planes (pure loads). 3-term fp32 emulation.
// 4 waves/block: (m_sub 2) x (n_sub 2), each wave 64x64 via 4x4 frags of 16x16x32.

__global__ __launch_bounds__(256) void k_gemm_mfma(const unsigned short* __restrict__ Ahi,
                                                   const unsigned short* __restrict__ Alo,
                                                   const short* __restrict__ BT_hi,
                                                   const short* __restrict__ BT_lo,
                                                   const float* __restrict__ dinv,
                                                   unsigned short* __restrict__ Cbf, int M) {
    const int tid  = threadIdx.x;
    const int wave = tid >> 6;
    const int lane = tid & 63;
    const int r16  = lane & 15;
    const int kg   = lane >> 4;              // k-group 0..3
    const int m0   = blockIdx.x * 128 + (wave >> 1) * 64;
    const int n0   = (wave & 1) * 64;

    f32x4 acc[4][4] = {};

    for (int kstep = 0; kstep < 4; ++kstep) {
        const int kb = kstep * 32 + kg * 8;

        bf16x8 ah[4], al[4];
        #pragma unroll
        for (int mi = 0; mi < 4; ++mi) {
            int row = m0 + mi * 16 + r16;
            if (row >= M) row = M - 1;
            size_t off = (size_t)row * 128 + kb;
            ah[mi] = *(const bf16x8*)(Ahi + off);
            al[mi] = *(const bf16x8*)(Alo + off);
        }
        bf16x8 bh[4], bl[4];
        #pragma unroll
        for (int ni = 0; ni < 4; ++ni) {
            int col = n0 + ni * 16 + r16;
            size_t idx = (size_t)col * 128 + kb;
            bh[ni] = *(const bf16x8*)(BT_hi + idx);
            bl[ni] = *(const bf16x8*)(BT_lo + idx);
        }
        #pragma unroll
        for (int mi = 0; mi < 4; ++mi)
            #pragma unroll
            for (int ni = 0; ni < 4; ++ni) {
                acc[mi][ni] = __builtin_amdgcn_mfma_f32_16x16x32_bf16(al[mi], bh[ni], acc[mi][ni], 0, 0, 0);
                acc[mi][ni] = __builtin_amdgcn_mfma_f32_16x16x32_bf16(ah[mi], bl[ni], acc[mi][ni], 0, 0, 0);
                acc[mi][ni] = __builtin_amdgcn_mfma_f32_16x16x32_bf16(ah[mi], bh[ni], acc[mi][ni], 0, 0, 0);
            }
    }

    // epilogue: D layout col=lane&15, row=(lane>>4)*4+reg ; scale by dinv[row], cast bf16
    #pragma unroll
    for (int mi = 0; mi < 4; ++mi) {
        #pragma unroll
        for (int r = 0; r < 4; ++r) {
            int row = m0 + mi * 16 + (lane >> 4) * 4 + r;
            if (row < M) {
                float dr = dinv[row];
                #pragma unroll
                for (int ni = 0; ni < 4; ++ni) {
                    int col = n0 + ni * 16 + r16;
                    Cbf[(size_t)row * 128 + col] = (unsigned short)f2bf(acc[mi][ni][r] * dr);
                }
            }
        }
    }
}

// ---------------- aggregation: 4 nodes/wave, 16 lanes x ushort8 (16B/lane) ----------
// out[i,:] = relu( dinv[i] * ( h'[i,:] + sum_{e: dst=i} h'[src_e,:] ) + b )
// MODE 0: write hi/lo bf16 planes (feeds next MFMA GEMM)
// MODE 1: write single bf16 plane (feeds head GEMM)

template <int MODE>
__global__ __launch_bounds__(256) void k_aggregate(const unsigned short* __restrict__ hp,
                                                   const int* __restrict__ row_start,
                                                   const int* __restrict__ edge_src,
                                                   const float* __restrict__ dinv,
                                                   const float* __restrict__ bias,
                                                   unsigned short* __restrict__ outHi,
                                                   unsigned short* __restrict__ outLo,
                                                   unsigned short* __restrict__ outBf, int n) {
    const int wave = (blockIdx.x * 256 + threadIdx.x) >> 6;
    const int sub  = (threadIdx.x >> 4) & 3;
    const int l16  = threadIdx.x & 15;
    const int i    = wave * 4 + sub;
    if (i >= n) return;

    const u16x8* __restrict__ h8 = (const u16x8*)hp;   // 16 x u16x8 per row

    u16x8 sv = h8[(size_t)i * 16 + l16];               // self term
    float a[8], b[8];
    #pragma unroll
    for (int q = 0; q < 8; ++q) { a[q] = bfu2f(sv[q]); b[q] = 0.f; }

    int j = row_start[i];
    const int e = row_start[i + 1];
    while (j < e) {
        const int e1 = e - 1;
        int j1 = j + 1, j2 = j + 2, j3 = j + 3;
        bool c1 = j1 < e, c2 = j2 < e, c3 = j3 < e;
        int s0i = edge_src[j];
        int s1i = edge_src[c1 ? j1 : e1];
        int s2i = edge_src[c2 ? j2 : e1];
        int s3i = edge_src[c3 ? j3 : e1];
        u16x8 v0 = h8[(size_t)s0i * 16 + l16];
        u16x8 v1 = h8[(size_t)s1i * 16 + l16];
        u16x8 v2 = h8[(size_t)s2i * 16 + l16];
        u16x8 v3 = h8[(size_t)s3i * 16 + l16];
        float m1 = c1 ? 1.f : 0.f, m2 = c2 ? 1.f : 0.f, m3 = c3 ? 1.f : 0.f;
        #pragma unroll
        for (int q = 0; q < 8; ++q) {
            a[q] += bfu2f(v0[q]);
            b[q] = fmaf(bfu2f(v1[q]), m1, b[q]);
            a[q] = fmaf(bfu2f(v2[q]), m2, a[q]);
            b[q] = fmaf(bfu2f(v3[q]), m3, b[q]);
        }
        j += 4;
    }

    const float di = dinv[i];
    float4 bs0 = ((const float4*)bias)[l16 * 2];
    float4 bs1 = ((const float4*)bias)[l16 * 2 + 1];
    float bb[8] = {bs0.x, bs0.y, bs0.z, bs0.w, bs1.x, bs1.y, bs1.z, bs1.w};
    float r[8];
    #pragma unroll
    for (int q = 0; q < 8; ++q)
        r[q] = fmaxf(fmaf(a[q] + b[q], di, bb[q]), 0.f);

    if (MODE == 0) {
        u16x8 hi, lo;
        #pragma unroll
        for (int q = 0; q < 8; ++q) {
            unsigned short h = (unsigned short)f2bf(r[q]);
            hi[q] = h;
            lo[q] = (unsigned short)f2bf(r[q] - bfu2f(h));
        }
        ((u16x8*)outHi)[(size_t)i * 16 + l16] = hi;
        ((u16x8*)outLo)[(size_t)i * 16 + l16] = lo;
    } else {
        u16x8 ov;
        #pragma unroll
        for (int q = 0; q < 8; ++q) ov[q] = (unsigned short)f2bf(r[q]);
        ((u16x8*)outBf)[(size_t)i * 16 + l16] = ov;
    }
}

// ---------------- head GEMM: out[M x 16] = bf16A[M x 128] * Wh[128 x 16] + bh ----------

__global__ __launch_bounds__(256) void k_gemm_head(const unsigned short* __restrict__ A,
                                                   const float* __restrict__ Wh,
                                                   const float* __restrict__ bh,
                                                   float* __restrict__ C, int M) {
    __shared__ float Ws[128 * 16];
    const int t = threadIdx.x;
    *(float4*)&Ws[t * 8]     = *(const float4*)&Wh[t * 8];
    *(float4*)&Ws[t * 8 + 4] = *(const float4*)&Wh[t * 8 + 4];
    __syncthreads();

    const int wave = t >> 6;
    const int lane = t & 63;
    const int r    = lane & 15;
    const int kq   = lane >> 4;
    int row = (blockIdx.x * 4 + wave) * 16 + r;
    int lrow = (row < M) ? row : (M - 1);

    const u16x8* ap = (const u16x8*)(A + (size_t)lrow * 128 + kq * 32);
    float acc[16] = {};
    #pragma unroll
    for (int k8 = 0; k8 < 4; ++k8) {
        u16x8 av = ap[k8];
        #pragma unroll
        for (int q = 0; q < 8; ++q) {
            int k = kq * 32 + k8 * 8 + q;
            float aval = bfu2f(av[q]);
            #pragma unroll
            for (int c = 0; c < 16; ++c)
                acc[c] = fmaf(aval, Ws[k * 16 + c], acc[c]);
        }
    }
    #pragma unroll
    for (int c = 0; c < 16; ++c) {
        acc[c] += __shfl_down(acc[c], 16);
        acc[c] += __shfl_down(acc[c], 32);
    }
    if (lane < 16 && row < M) {
        float* orow = C + (size_t)row * 16;
        #pragma unroll
        for (int c = 0; c < 16; c += 4) {
            float4 v = make_float4(acc[c] + bh[c], acc[c + 1] + bh[c + 1],
                                   acc[c + 2] + bh[c + 2], acc[c + 3] + bh[c + 3]);
            *(float4*)(orow + c) = v;
        }
    }
}

// ---------------- launch ----------------

extern "C" void kernel_launch(void* const* d_in, const int* in_sizes, int n_in,
                              void* d_out, int out_size, void* d_ws, size_t ws_size,
                              hipStream_t stream) {
    const float* x  = (const float*)d_in[0];
    const float* W1 = (const float*)d_in[1];
    const float* b1 = (const float*)d_in[2];
    const float* W2 = (const float*)d_in[3];
    const float* b2 = (const float*)d_in[4];
    const float* Wh = (const float*)d_in[5];
    const float* bh = (const float*)d_in[6];
    const int*   ei = (const int*)d_in[7];

    const int N = in_sizes[0] / 128;
    const int E = in_sizes[7] / 2;
    const int* src = ei;
    const int* dst = ei + E;
    float* out = (float*)d_out;

    char* w = (char*)d_ws;
    auto alloc = [&](size_t bytes) -> void* {
        void* p = (void*)w;
        w += (bytes + 255) & ~(size_t)255;
        return p;
    };
    unsigned short* planeHi   = (unsigned short*)alloc((size_t)N * 128 * sizeof(short));
    unsigned short* planeLo   = (unsigned short*)alloc((size_t)N * 128 * sizeof(short));
    unsigned short* hp        = (unsigned short*)alloc((size_t)N * 128 * sizeof(short));
    unsigned short* h2bf      = (unsigned short*)alloc((size_t)N * 128 * sizeof(short));
    int*   indeg     = (int*)alloc((size_t)N * sizeof(int));
    int*   row_start = (int*)alloc((size_t)(N + 1) * sizeof(int));
    float* dinv      = (float*)alloc((size_t)N * sizeof(float));
    int*   tilesums  = (int*)alloc(128 * sizeof(int));
    int*   edge_src  = (int*)alloc((size_t)E * sizeof(int));
    int*   rank      = (int*)alloc((size_t)E * sizeof(int));
    short* w1hiT     = (short*)alloc(128 * 128 * sizeof(short));
    short* w1loT     = (short*)alloc(128 * 128 * sizeof(short));
    short* w2hiT     = (short*)alloc(128 * 128 * sizeof(short));
    short* w2loT     = (short*)alloc(128 * 128 * sizeof(short));

    hipMemsetAsync(indeg, 0, (size_t)N * sizeof(int), stream);

    // CSR build (graph identical for both layers)
    k_count_rank<<<(E + 255) / 256, 256, 0, stream>>>(dst, indeg, rank, E);
    const int nTiles = (N + 1023) / 1024;
    k_scan1<<<nTiles, 256, 0, stream>>>(indeg, row_start, tilesums, N);
    k_scan2<<<1, 128, 0, stream>>>(tilesums, nTiles);
    k_scan3_dinv<<<(N + 255) / 256, 256, 0, stream>>>(row_start, tilesums, indeg, dinv, N, E);
    k_fill_rank<<<(E + 255) / 256, 256, 0, stream>>>(src, dst, rank, row_start, edge_src, E);

    // weight + activation splits
    k_wsplit<<<64, 256, 0, stream>>>(W1, w1hiT, w1loT);
    k_wsplit<<<64, 256, 0, stream>>>(W2, w2hiT, w2loT);
    const int total4 = N * 32;   // N*128/4
    k_xsplit<<<(total4 + 255) / 256, 256, 0, stream>>>(x, planeHi, planeLo, total4);

    const int gblocks = (N + 127) / 128;
    const int ablocks = (N + 15) / 16;
    // layer 1
    k_gemm_mfma<<<gblocks, 256, 0, stream>>>(planeHi, planeLo, w1hiT, w1loT, dinv, hp, N);
    k_aggregate<0><<<ablocks, 256, 0, stream>>>(hp, row_start, edge_src, dinv, b1,
                                                planeHi, planeLo, nullptr, N);
    // layer 2
    k_gemm_mfma<<<gblocks, 256, 0, stream>>>(planeHi, planeLo, w2hiT, w2loT, dinv, hp, N);
    k_aggregate<1><<<ablocks, 256, 0, stream>>>(hp, row_start, edge_src, dinv, b2,
                                                nullptr, nullptr, h2bf, N);
    // head
    k_gemm_head<<<(N + 63) / 64, 256, 0, stream>>>(h2bf, Wh, bh, out, N);
}

// Round 6
// 231.339 us; speedup vs baseline: 1.5811x; 1.0854x over previous
//
#include <hip/hip_runtime.h>
#include <hip/hip_bf16.h>

typedef short bf16x8 __attribute__((ext_vector_type(8)));
typedef unsigned short u16x8 __attribute__((ext_vector_type(8)));
typedef float f32x4 __attribute__((ext_vector_type(4)));

// ---------- bf16 helpers ----------
static __device__ __forceinline__ short f2bf(float f) {
    union { float f; unsigned u; } v; v.f = f;
    unsigned r = v.u + 0x7FFF + ((v.u >> 16) & 1);   // RNE
    return (short)(r >> 16);
}
static __device__ __forceinline__ float bf2f(short h) {
    union { unsigned u; float f; } v;
    v.u = ((unsigned)(unsigned short)h) << 16;
    return v.f;
}
static __device__ __forceinline__ float bfu2f(unsigned short h) {
    union { unsigned u; float f; } v;
    v.u = ((unsigned)h) << 16;
    return v.f;
}

// ---------------- CSR build ----------------

__global__ void k_count_rank(const int* __restrict__ dst, int* __restrict__ indeg,
                             int* __restrict__ rank, int E) {
    int e = blockIdx.x * 256 + threadIdx.x;
    if (e < E) rank[e] = atomicAdd(&indeg[dst[e]], 1);
}

__global__ void k_scan1(const int* __restrict__ in, int* __restrict__ out,
                        int* __restrict__ sums, int n) {
    __shared__ int lds[256];
    const int t = threadIdx.x;
    const int base = blockIdx.x * 1024 + t * 4;
    int v0 = (base + 0 < n) ? in[base + 0] : 0;
    int v1 = (base + 1 < n) ? in[base + 1] : 0;
    int v2 = (base + 2 < n) ? in[base + 2] : 0;
    int v3 = (base + 3 < n) ? in[base + 3] : 0;
    const int tsum = v0 + v1 + v2 + v3;
    lds[t] = tsum;
    __syncthreads();
    #pragma unroll
    for (int off = 1; off < 256; off <<= 1) {
        int x = (t >= off) ? lds[t - off] : 0;
        __syncthreads();
        lds[t] += x;
        __syncthreads();
    }
    int excl = lds[t] - tsum;
    if (base + 0 < n) out[base + 0] = excl;  excl += v0;
    if (base + 1 < n) out[base + 1] = excl;  excl += v1;
    if (base + 2 < n) out[base + 2] = excl;  excl += v2;
    if (base + 3 < n) out[base + 3] = excl;
    if (t == 255) sums[blockIdx.x] = lds[255];
}

__global__ void k_scan2(int* __restrict__ sums, int nt) {
    __shared__ int lds[128];
    const int t = threadIdx.x;
    int v = (t < nt) ? sums[t] : 0;
    lds[t] = v;
    __syncthreads();
    #pragma unroll
    for (int off = 1; off < 128; off <<= 1) {
        int x = (t >= off) ? lds[t - off] : 0;
        __syncthreads();
        lds[t] += x;
        __syncthreads();
    }
    if (t < nt) sums[t] = lds[t] - v;
}

__global__ void k_scan3_dinv(int* __restrict__ row_start, const int* __restrict__ sums,
                             const int* __restrict__ indeg, float* __restrict__ dinv,
                             int n, int E) {
    int i = blockIdx.x * 256 + threadIdx.x;
    if (i < n) {
        row_start[i] += sums[i >> 10];
        dinv[i] = rsqrtf((float)indeg[i] + 1.0f);   // +1 self-loop
    }
    if (i == 0) row_start[n] = E;
}

__global__ void k_fill_rank(const int* __restrict__ src, const int* __restrict__ dst,
                            const int* __restrict__ rank, const int* __restrict__ row_start,
                            int* __restrict__ edge_src, int E) {
    int e = blockIdx.x * 256 + threadIdx.x;
    if (e >= E) return;
    edge_src[row_start[dst[e]] + rank[e]] = src[e];
}

// ---------------- weight split: W[128][128] fp32 -> W^T hi/lo bf16 ----------------

__global__ void k_wsplit(const float* __restrict__ W, short* __restrict__ WT_hi,
                         short* __restrict__ WT_lo) {
    int idx = blockIdx.x * 256 + threadIdx.x;   // 16384
    int k = idx >> 7, n = idx & 127;
    float v = W[idx];
    short h = f2bf(v);
    short l = f2bf(v - bf2f(h));
    WT_hi[n * 128 + k] = h;
    WT_lo[n * 128 + k] = l;
}

// ---------------- x convert: fp32 -> bf16 plane ----------------

__global__ void k_xbf16(const float* __restrict__ X, unsigned short* __restrict__ Xbf,
                        int total8) {
    int idx = blockIdx.x * 256 + threadIdx.x;   // 8 floats per thread
    if (idx >= total8) return;
    float4 v0 = ((const float4*)X)[idx * 2];
    float4 v1 = ((const float4*)X)[idx * 2 + 1];
    u16x8 o;
    o[0] = (unsigned short)f2bf(v0.x); o[1] = (unsigned short)f2bf(v0.y);
    o[2] = (unsigned short)f2bf(v0.z); o[3] = (unsigned short)f2bf(v0.w);
    o[4] = (unsigned short)f2bf(v1.x); o[5] = (unsigned short)f2bf(v1.y);
    o[6] = (unsigned short)f2bf(v1.z); o[7] = (unsigned short)f2bf(v1.w);
    ((u16x8*)Xbf)[idx] = o;
}

// ---------------- MFMA GEMM: Cbf[M x 128] = bf16( (Abf @ B) * dinv[row] ) ----------
// 2-term: A bf16 (exactly-representable input), B split hi/lo -> A @ (Bh + Bl).
// All 16 A fragments loaded up front (max MLP); B double-buffered from L2.
// 4 waves/block: (m 2) x (n 2), each wave 64x64 via 4x4 frags of 16x16x32.

__global__ __launch_bounds__(256) void k_gemm_mfma(const unsigned short* __restrict__ Abf,
                                                   const short* __restrict__ BT_hi,
                                                   const short* __restrict__ BT_lo,
                                                   const float* __restrict__ dinv,
                                                   unsigned short* __restrict__ Cbf, int M) {
    const int tid  = threadIdx.x;
    const int wave = tid >> 6;
    const int lane = tid & 63;
    const int r16  = lane & 15;
    const int kg   = lane >> 4;              // k-group 0..3
    const int m0   = blockIdx.x * 128 + (wave >> 1) * 64;
    const int n0   = (wave & 1) * 64;

    // ---- issue ALL A loads up front: 16 x 16B per lane in flight ----
    bf16x8 a[4][4];                           // [kstep][mi]
    #pragma unroll
    for (int ks = 0; ks < 4; ++ks) {
        #pragma unroll
        for (int mi = 0; mi < 4; ++mi) {
            int row = m0 + mi * 16 + r16;
            if (row >= M) row = M - 1;
            a[ks][mi] = *(const bf16x8*)(Abf + (size_t)row * 128 + ks * 32 + kg * 8);
        }
    }

    // ---- B double-buffer (L2-resident weights) ----
    bf16x8 bufh[2][4], bufl[2][4];
    #pragma unroll
    for (int ni = 0; ni < 4; ++ni) {
        size_t idx = (size_t)(n0 + ni * 16 + r16) * 128 + kg * 8;
        bufh[0][ni] = *(const bf16x8*)(BT_hi + idx);
        bufl[0][ni] = *(const bf16x8*)(BT_lo + idx);
    }

    f32x4 acc[4][4] = {};

    #pragma unroll
    for (int ks = 0; ks < 4; ++ks) {
        const int cur = ks & 1, nxt = cur ^ 1;
        if (ks < 3) {
            #pragma unroll
            for (int ni = 0; ni < 4; ++ni) {
                size_t idx = (size_t)(n0 + ni * 16 + r16) * 128 + (ks + 1) * 32 + kg * 8;
                bufh[nxt][ni] = *(const bf16x8*)(BT_hi + idx);
                bufl[nxt][ni] = *(const bf16x8*)(BT_lo + idx);
            }
        }
        #pragma unroll
        for (int mi = 0; mi < 4; ++mi)
            #pragma unroll
            for (int ni = 0; ni < 4; ++ni) {
                acc[mi][ni] = __builtin_amdgcn_mfma_f32_16x16x32_bf16(a[ks][mi], bufl[cur][ni], acc[mi][ni], 0, 0, 0);
                acc[mi][ni] = __builtin_amdgcn_mfma_f32_16x16x32_bf16(a[ks][mi], bufh[cur][ni], acc[mi][ni], 0, 0, 0);
            }
    }

    // epilogue: D layout col=lane&15, row=(lane>>4)*4+reg ; scale by dinv[row], cast bf16
    #pragma unroll
    for (int mi = 0; mi < 4; ++mi) {
        #pragma unroll
        for (int r = 0; r < 4; ++r) {
            int row = m0 + mi * 16 + (lane >> 4) * 4 + r;
            if (row < M) {
                float dr = dinv[row];
                #pragma unroll
                for (int ni = 0; ni < 4; ++ni) {
                    int col = n0 + ni * 16 + r16;
                    Cbf[(size_t)row * 128 + col] = (unsigned short)f2bf(acc[mi][ni][r] * dr);
                }
            }
        }
    }
}

// ---------------- aggregation: 4 nodes/wave, 16 lanes x ushort8 (16B/lane) ----------
// outBf[i,:] = bf16( relu( dinv[i] * ( h'[i,:] + sum_{e: dst=i} h'[src_e,:] ) + b ) )

__global__ __launch_bounds__(256) void k_aggregate(const unsigned short* __restrict__ hp,
                                                   const int* __restrict__ row_start,
                                                   const int* __restrict__ edge_src,
                                                   const float* __restrict__ dinv,
                                                   const float* __restrict__ bias,
                                                   unsigned short* __restrict__ outBf, int n) {
    const int wave = (blockIdx.x * 256 + threadIdx.x) >> 6;
    const int sub  = (threadIdx.x >> 4) & 3;
    const int l16  = threadIdx.x & 15;
    const int i    = wave * 4 + sub;
    if (i >= n) return;

    const u16x8* __restrict__ h8 = (const u16x8*)hp;   // 16 x u16x8 per row

    u16x8 sv = h8[(size_t)i * 16 + l16];               // self term
    float a[8], b[8];
    #pragma unroll
    for (int q = 0; q < 8; ++q) { a[q] = bfu2f(sv[q]); b[q] = 0.f; }

    int j = row_start[i];
    const int e = row_start[i + 1];
    while (j < e) {
        const int e1 = e - 1;
        int j1 = j + 1, j2 = j + 2, j3 = j + 3;
        bool c1 = j1 < e, c2 = j2 < e, c3 = j3 < e;
        int s0i = edge_src[j];
        int s1i = edge_src[c1 ? j1 : e1];
        int s2i = edge_src[c2 ? j2 : e1];
        int s3i = edge_src[c3 ? j3 : e1];
        u16x8 v0 = h8[(size_t)s0i * 16 + l16];
        u16x8 v1 = h8[(size_t)s1i * 16 + l16];
        u16x8 v2 = h8[(size_t)s2i * 16 + l16];
        u16x8 v3 = h8[(size_t)s3i * 16 + l16];
        float m1 = c1 ? 1.f : 0.f, m2 = c2 ? 1.f : 0.f, m3 = c3 ? 1.f : 0.f;
        #pragma unroll
        for (int q = 0; q < 8; ++q) {
            a[q] += bfu2f(v0[q]);
            b[q] = fmaf(bfu2f(v1[q]), m1, b[q]);
            a[q] = fmaf(bfu2f(v2[q]), m2, a[q]);
            b[q] = fmaf(bfu2f(v3[q]), m3, b[q]);
        }
        j += 4;
    }

    const float di = dinv[i];
    float4 bs0 = ((const float4*)bias)[l16 * 2];
    float4 bs1 = ((const float4*)bias)[l16 * 2 + 1];
    float bb[8] = {bs0.x, bs0.y, bs0.z, bs0.w, bs1.x, bs1.y, bs1.z, bs1.w};
    u16x8 ov;
    #pragma unroll
    for (int q = 0; q < 8; ++q) {
        float r = fmaxf(fmaf(a[q] + b[q], di, bb[q]), 0.f);
        ov[q] = (unsigned short)f2bf(r);
    }
    ((u16x8*)outBf)[(size_t)i * 16 + l16] = ov;
}

// ---------------- head GEMM: out[M x 16] = bf16A[M x 128] * Wh[128 x 16] + bh ----------

__global__ __launch_bounds__(256) void k_gemm_head(const unsigned short* __restrict__ A,
                                                   const float* __restrict__ Wh,
                                                   const float* __restrict__ bh,
                                                   float* __restrict__ C, int M) {
    __shared__ float Ws[128 * 16];
    const int t = threadIdx.x;
    *(float4*)&Ws[t * 8]     = *(const float4*)&Wh[t * 8];
    *(float4*)&Ws[t * 8 + 4] = *(const float4*)&Wh[t * 8 + 4];
    __syncthreads();

    const int wave = t >> 6;
    const int lane = t & 63;
    const int r    = lane & 15;
    const int kq   = lane >> 4;
    int row = (blockIdx.x * 4 + wave) * 16 + r;
    int lrow = (row < M) ? row : (M - 1);

    const u16x8* ap = (const u16x8*)(A + (size_t)lrow * 128 + kq * 32);
    float acc[16] = {};
    #pragma unroll
    for (int k8 = 0; k8 < 4; ++k8) {
        u16x8 av = ap[k8];
        #pragma unroll
        for (int q = 0; q < 8; ++q) {
            int k = kq * 32 + k8 * 8 + q;
            float aval = bfu2f(av[q]);
            #pragma unroll
            for (int c = 0; c < 16; ++c)
                acc[c] = fmaf(aval, Ws[k * 16 + c], acc[c]);
        }
    }
    #pragma unroll
    for (int c = 0; c < 16; ++c) {
        acc[c] += __shfl_down(acc[c], 16);
        acc[c] += __shfl_down(acc[c], 32);
    }
    if (lane < 16 && row < M) {
        float* orow = C + (size_t)row * 16;
        #pragma unroll
        for (int c = 0; c < 16; c += 4) {
            float4 v = make_float4(acc[c] + bh[c], acc[c + 1] + bh[c + 1],
                                   acc[c + 2] + bh[c + 2], acc[c + 3] + bh[c + 3]);
            *(float4*)(orow + c) = v;
        }
    }
}

// ---------------- launch ----------------

extern "C" void kernel_launch(void* const* d_in, const int* in_sizes, int n_in,
                              void* d_out, int out_size, void* d_ws, size_t ws_size,
                              hipStream_t stream) {
    const float* x  = (const float*)d_in[0];
    const float* W1 = (const float*)d_in[1];
    const float* b1 = (const float*)d_in[2];
    const float* W2 = (const float*)d_in[3];
    const float* b2 = (const float*)d_in[4];
    const float* Wh = (const float*)d_in[5];
    const float* bh = (const float*)d_in[6];
    const int*   ei = (const int*)d_in[7];

    const int N = in_sizes[0] / 128;
    const int E = in_sizes[7] / 2;
    const int* src = ei;
    const int* dst = ei + E;
    float* out = (float*)d_out;

    char* w = (char*)d_ws;
    auto alloc = [&](size_t bytes) -> void* {
        void* p = (void*)w;
        w += (bytes + 255) & ~(size_t)255;
        return p;
    };
    unsigned short* actA      = (unsigned short*)alloc((size_t)N * 128 * sizeof(short));
    unsigned short* hp        = (unsigned short*)alloc((size_t)N * 128 * sizeof(short));
    unsigned short* actB      = (unsigned short*)alloc((size_t)N * 128 * sizeof(short));
    int*   indeg     = (int*)alloc((size_t)N * sizeof(int));
    int*   row_start = (int*)alloc((size_t)(N + 1) * sizeof(int));
    float* dinv      = (float*)alloc((size_t)N * sizeof(float));
    int*   tilesums  = (int*)alloc(128 * sizeof(int));
    int*   edge_src  = (int*)alloc((size_t)E * sizeof(int));
    int*   rank      = (int*)alloc((size_t)E * sizeof(int));
    short* w1hiT     = (short*)alloc(128 * 128 * sizeof(short));
    short* w1loT     = (short*)alloc(128 * 128 * sizeof(short));
    short* w2hiT     = (short*)alloc(128 * 128 * sizeof(short));
    short* w2loT     = (short*)alloc(128 * 128 * sizeof(short));

    hipMemsetAsync(indeg, 0, (size_t)N * sizeof(int), stream);

    // CSR build (graph identical for both layers)
    k_count_rank<<<(E + 255) / 256, 256, 0, stream>>>(dst, indeg, rank, E);
    const int nTiles = (N + 1023) / 1024;
    k_scan1<<<nTiles, 256, 0, stream>>>(indeg, row_start, tilesums, N);
    k_scan2<<<1, 128, 0, stream>>>(tilesums, nTiles);
    k_scan3_dinv<<<(N + 255) / 256, 256, 0, stream>>>(row_start, tilesums, indeg, dinv, N, E);
    k_fill_rank<<<(E + 255) / 256, 256, 0, stream>>>(src, dst, rank, row_start, edge_src, E);

    // weight splits + x convert
    k_wsplit<<<64, 256, 0, stream>>>(W1, w1hiT, w1loT);
    k_wsplit<<<64, 256, 0, stream>>>(W2, w2hiT, w2loT);
    const int total8 = N * 16;   // N*128/8
    k_xbf16<<<(total8 + 255) / 256, 256, 0, stream>>>(x, actA, total8);

    const int gblocks = (N + 127) / 128;
    const int ablocks = (N + 15) / 16;
    // layer 1
    k_gemm_mfma<<<gblocks, 256, 0, stream>>>(actA, w1hiT, w1loT, dinv, hp, N);
    k_aggregate<<<ablocks, 256, 0, stream>>>(hp, row_start, edge_src, dinv, b1, actB, N);
    // layer 2
    k_gemm_mfma<<<gblocks, 256, 0, stream>>>(actB, w2hiT, w2loT, dinv, hp, N);
    k_aggregate<<<ablocks, 256, 0, stream>>>(hp, row_start, edge_src, dinv, b2, actA, N);
    // head
    k_gemm_head<<<(N + 63) / 64, 256, 0, stream>>>(actA, Wh, bh, out, N);
}

// Round 7
// 209.157 us; speedup vs baseline: 1.7488x; 1.1061x over previous
//
#include <hip/hip_runtime.h>
#include <hip/hip_bf16.h>

typedef short bf16x8 __attribute__((ext_vector_type(8)));
typedef unsigned short u16x8 __attribute__((ext_vector_type(8)));
typedef float f32x4 __attribute__((ext_vector_type(4)));

// ---------- bf16 helpers ----------
static __device__ __forceinline__ short f2bf(float f) {
    union { float f; unsigned u; } v; v.f = f;
    unsigned r = v.u + 0x7FFF + ((v.u >> 16) & 1);   // RNE
    return (short)(r >> 16);
}
static __device__ __forceinline__ float bf2f(short h) {
    union { unsigned u; float f; } v;
    v.u = ((unsigned)(unsigned short)h) << 16;
    return v.f;
}
static __device__ __forceinline__ float bfu2f(unsigned short h) {
    union { unsigned u; float f; } v;
    v.u = ((unsigned)h) << 16;
    return v.f;
}

// ---------------- CSR build ----------------

__global__ void k_count_rank(const int* __restrict__ dst, int* __restrict__ indeg,
                             int* __restrict__ rank, int E) {
    int e = blockIdx.x * 256 + threadIdx.x;
    if (e < E) rank[e] = atomicAdd(&indeg[dst[e]], 1);
}

__global__ void k_scan1(const int* __restrict__ in, int* __restrict__ out,
                        int* __restrict__ sums, int n) {
    __shared__ int lds[256];
    const int t = threadIdx.x;
    const int base = blockIdx.x * 1024 + t * 4;
    int v0 = (base + 0 < n) ? in[base + 0] : 0;
    int v1 = (base + 1 < n) ? in[base + 1] : 0;
    int v2 = (base + 2 < n) ? in[base + 2] : 0;
    int v3 = (base + 3 < n) ? in[base + 3] : 0;
    const int tsum = v0 + v1 + v2 + v3;
    lds[t] = tsum;
    __syncthreads();
    #pragma unroll
    for (int off = 1; off < 256; off <<= 1) {
        int x = (t >= off) ? lds[t - off] : 0;
        __syncthreads();
        lds[t] += x;
        __syncthreads();
    }
    int excl = lds[t] - tsum;
    if (base + 0 < n) out[base + 0] = excl;  excl += v0;
    if (base + 1 < n) out[base + 1] = excl;  excl += v1;
    if (base + 2 < n) out[base + 2] = excl;  excl += v2;
    if (base + 3 < n) out[base + 3] = excl;
    if (t == 255) sums[blockIdx.x] = lds[255];
}

__global__ void k_scan2(int* __restrict__ sums, int nt) {
    __shared__ int lds[128];
    const int t = threadIdx.x;
    int v = (t < nt) ? sums[t] : 0;
    lds[t] = v;
    __syncthreads();
    #pragma unroll
    for (int off = 1; off < 128; off <<= 1) {
        int x = (t >= off) ? lds[t - off] : 0;
        __syncthreads();
        lds[t] += x;
        __syncthreads();
    }
    if (t < nt) sums[t] = lds[t] - v;
}

__global__ void k_scan3_dinv(int* __restrict__ row_start, const int* __restrict__ sums,
                             const int* __restrict__ indeg, float* __restrict__ dinv,
                             int n, int E) {
    int i = blockIdx.x * 256 + threadIdx.x;
    if (i < n) {
        row_start[i] += sums[i >> 10];
        dinv[i] = rsqrtf((float)indeg[i] + 1.0f);   // +1 self-loop
    }
    if (i == 0) row_start[n] = E;
}

__global__ void k_fill_rank(const int* __restrict__ src, const int* __restrict__ dst,
                            const int* __restrict__ rank, const int* __restrict__ row_start,
                            int* __restrict__ edge_src, int E) {
    int e = blockIdx.x * 256 + threadIdx.x;
    if (e >= E) return;
    edge_src[row_start[dst[e]] + rank[e]] = src[e];
}

// ---------------- weight split -> PANEL layout ----------------
// Bp unit u = nb*256 + k8*16 + c16 holds W[k8*8 .. k8*8+8][nb*16+c16] (hi/lo bf16).
// A wave's B-fragment load (4 quarter-waves x 16 lanes) is 1KB CONTIGUOUS.

__global__ void k_wsplit_panel(const float* __restrict__ W, short* __restrict__ Bp_hi,
                               short* __restrict__ Bp_lo) {
    int u = blockIdx.x * 256 + threadIdx.x;     // 2048 units
    int nb = u >> 8, k8 = (u >> 4) & 15, c16 = u & 15;
    int col = nb * 16 + c16, k0 = k8 * 8;
    bf16x8 h, l;
    #pragma unroll
    for (int j = 0; j < 8; ++j) {
        float v = W[(size_t)(k0 + j) * 128 + col];
        short hh = f2bf(v);
        h[j] = hh;
        l[j] = f2bf(v - bf2f(hh));
    }
    *(bf16x8*)(Bp_hi + (size_t)u * 8) = h;
    *(bf16x8*)(Bp_lo + (size_t)u * 8) = l;
}

// ---------------- x convert: fp32 -> bf16 plane ----------------

__global__ void k_xbf16(const float* __restrict__ X, unsigned short* __restrict__ Xbf,
                        int total8) {
    int idx = blockIdx.x * 256 + threadIdx.x;   // 8 floats per thread
    if (idx >= total8) return;
    float4 v0 = ((const float4*)X)[idx * 2];
    float4 v1 = ((const float4*)X)[idx * 2 + 1];
    u16x8 o;
    o[0] = (unsigned short)f2bf(v0.x); o[1] = (unsigned short)f2bf(v0.y);
    o[2] = (unsigned short)f2bf(v0.z); o[3] = (unsigned short)f2bf(v0.w);
    o[4] = (unsigned short)f2bf(v1.x); o[5] = (unsigned short)f2bf(v1.y);
    o[6] = (unsigned short)f2bf(v1.z); o[7] = (unsigned short)f2bf(v1.w);
    ((u16x8*)Xbf)[idx] = o;
}

// ---------------- MFMA GEMM: Cbf[M x 128] = bf16( (Abf @ B) * dinv[row] ) ----------
// A staged through LDS: coalesced 16B/lane global loads, XOR-swizzled ds_write/read
// (unit = row*16 + (chunk ^ (row&7)), 2-way banks max). B from panel layout: fully
// coalesced 1KB register loads, double-buffered. 2-term: A bf16 exact, B hi+lo.

__global__ __launch_bounds__(256) void k_gemm_mfma(const unsigned short* __restrict__ Abf,
                                                   const short* __restrict__ Bp_hi,
                                                   const short* __restrict__ Bp_lo,
                                                   const float* __restrict__ dinv,
                                                   unsigned short* __restrict__ Cbf, int M) {
    __shared__ unsigned short As[128 * 128];    // 32 KB, 16B units, swizzled
    const int tid  = threadIdx.x;
    const int wave = tid >> 6;
    const int lane = tid & 63;
    const int r16  = lane & 15;
    const int kg   = lane >> 4;                 // k-group 0..3
    const int m0   = blockIdx.x * 128;
    const int mh   = (wave >> 1) * 64;          // m-half base within tile
    const int nb0  = (wave & 1) * 4;            // n-half: panel blocks 0..3 / 4..7

    // ---- stage A tile: 8 rounds x 256 threads x 16B, coalesced ----
    #pragma unroll
    for (int rr = 0; rr < 8; ++rr) {
        int u = rr * 256 + tid;
        int row = u >> 4, c = u & 15;
        int rowg = m0 + row;
        if (rowg >= M) rowg = M - 1;
        bf16x8 v = *(const bf16x8*)(Abf + (size_t)rowg * 128 + c * 8);
        *(bf16x8*)(As + (size_t)(row * 16 + (c ^ (row & 7))) * 8) = v;
    }

    // ---- prefetch B kstep 0 (contiguous 1KB per instr, L2-resident) ----
    bf16x8 bufh[2][4], bufl[2][4];
    #pragma unroll
    for (int ni = 0; ni < 4; ++ni) {
        size_t uB = (size_t)(nb0 + ni) * 256 + (size_t)kg * 16 + r16;
        bufh[0][ni] = *(const bf16x8*)(Bp_hi + uB * 8);
        bufl[0][ni] = *(const bf16x8*)(Bp_lo + uB * 8);
    }

    __syncthreads();

    f32x4 acc[4][4] = {};

    #pragma unroll
    for (int ks = 0; ks < 4; ++ks) {
        const int cur = ks & 1, nxt = cur ^ 1;
        if (ks < 3) {
            #pragma unroll
            for (int ni = 0; ni < 4; ++ni) {
                size_t uB = (size_t)(nb0 + ni) * 256 + (size_t)((ks + 1) * 4 + kg) * 16 + r16;
                bufh[nxt][ni] = *(const bf16x8*)(Bp_hi + uB * 8);
                bufl[nxt][ni] = *(const bf16x8*)(Bp_lo + uB * 8);
            }
        }
        // A fragments from LDS (swizzled)
        bf16x8 a[4];
        const int c = ks * 4 + kg;
        #pragma unroll
        for (int mi = 0; mi < 4; ++mi) {
            int row = mh + mi * 16 + r16;
            a[mi] = *(const bf16x8*)(As + (size_t)(row * 16 + (c ^ (row & 7))) * 8);
        }
        #pragma unroll
        for (int mi = 0; mi < 4; ++mi)
            #pragma unroll
            for (int ni = 0; ni < 4; ++ni) {
                acc[mi][ni] = __builtin_amdgcn_mfma_f32_16x16x32_bf16(a[mi], bufl[cur][ni], acc[mi][ni], 0, 0, 0);
                acc[mi][ni] = __builtin_amdgcn_mfma_f32_16x16x32_bf16(a[mi], bufh[cur][ni], acc[mi][ni], 0, 0, 0);
            }
    }

    // epilogue: D layout col=lane&15, row=(lane>>4)*4+reg ; scale by dinv[row], cast bf16
    const int n0 = (wave & 1) * 64;
    #pragma unroll
    for (int mi = 0; mi < 4; ++mi) {
        #pragma unroll
        for (int r = 0; r < 4; ++r) {
            int row = m0 + mh + mi * 16 + (lane >> 4) * 4 + r;
            if (row < M) {
                float dr = dinv[row];
                #pragma unroll
                for (int ni = 0; ni < 4; ++ni) {
                    int col = n0 + ni * 16 + r16;
                    Cbf[(size_t)row * 128 + col] = (unsigned short)f2bf(acc[mi][ni][r] * dr);
                }
            }
        }
    }
}

// ---------------- aggregation: 4 nodes/wave, 16 lanes x ushort8, 8-wide gather ----
// outBf[i,:] = bf16( relu( dinv[i] * ( h'[i,:] + sum_{e: dst=i} h'[src_e,:] ) + b ) )

__global__ __launch_bounds__(256) void k_aggregate(const unsigned short* __restrict__ hp,
                                                   const int* __restrict__ row_start,
                                                   const int* __restrict__ edge_src,
                                                   const float* __restrict__ dinv,
                                                   const float* __restrict__ bias,
                                                   unsigned short* __restrict__ outBf, int n) {
    const int wave = (blockIdx.x * 256 + threadIdx.x) >> 6;
    const int sub  = (threadIdx.x >> 4) & 3;
    const int l16  = threadIdx.x & 15;
    const int i    = wave * 4 + sub;
    if (i >= n) return;

    const u16x8* __restrict__ h8 = (const u16x8*)hp;   // 16 x u16x8 per row

    u16x8 sv = h8[(size_t)i * 16 + l16];               // self term
    float a[8], b[8];
    #pragma unroll
    for (int q = 0; q < 8; ++q) { a[q] = bfu2f(sv[q]); b[q] = 0.f; }

    int j = row_start[i];
    const int e = row_start[i + 1];
    while (j < e) {
        const int e1 = e - 1;
        int   idx[8];
        float m[8];
        #pragma unroll
        for (int t = 0; t < 8; ++t) {
            int jt = j + t;
            bool ct = jt < e;
            idx[t] = edge_src[ct ? jt : e1];
            m[t] = ct ? 1.f : 0.f;
        }
        u16x8 v[8];
        #pragma unroll
        for (int t = 0; t < 8; ++t) v[t] = h8[(size_t)idx[t] * 16 + l16];
        #pragma unroll
        for (int t = 0; t < 8; t += 2) {
            #pragma unroll
            for (int q = 0; q < 8; ++q) {
                a[q] = fmaf(bfu2f(v[t][q]),     m[t],     a[q]);
                b[q] = fmaf(bfu2f(v[t + 1][q]), m[t + 1], b[q]);
            }
        }
        j += 8;
    }

    const float di = dinv[i];
    float4 bs0 = ((const float4*)bias)[l16 * 2];
    float4 bs1 = ((const float4*)bias)[l16 * 2 + 1];
    float bb[8] = {bs0.x, bs0.y, bs0.z, bs0.w, bs1.x, bs1.y, bs1.z, bs1.w};
    u16x8 ov;
    #pragma unroll
    for (int q = 0; q < 8; ++q) {
        float r = fmaxf(fmaf(a[q] + b[q], di, bb[q]), 0.f);
        ov[q] = (unsigned short)f2bf(r);
    }
    ((u16x8*)outBf)[(size_t)i * 16 + l16] = ov;
}

// ---------------- head GEMM: out[M x 16] = bf16A[M x 128] * Wh[128 x 16] + bh ----------

__global__ __launch_bounds__(256) void k_gemm_head(const unsigned short* __restrict__ A,
                                                   const float* __restrict__ Wh,
                                                   const float* __restrict__ bh,
                                                   float* __restrict__ C, int M) {
    __shared__ float Ws[128 * 16];
    const int t = threadIdx.x;
    *(float4*)&Ws[t * 8]     = *(const float4*)&Wh[t * 8];
    *(float4*)&Ws[t * 8 + 4] = *(const float4*)&Wh[t * 8 + 4];
    __syncthreads();

    const int wave = t >> 6;
    const int lane = t & 63;
    const int r    = lane & 15;
    const int kq   = lane >> 4;
    int row = (blockIdx.x * 4 + wave) * 16 + r;
    int lrow = (row < M) ? row : (M - 1);

    const u16x8* ap = (const u16x8*)(A + (size_t)lrow * 128 + kq * 32);
    float acc[16] = {};
    #pragma unroll
    for (int k8 = 0; k8 < 4; ++k8) {
        u16x8 av = ap[k8];
        #pragma unroll
        for (int q = 0; q < 8; ++q) {
            int k = kq * 32 + k8 * 8 + q;
            float aval = bfu2f(av[q]);
            #pragma unroll
            for (int c = 0; c < 16; ++c)
                acc[c] = fmaf(aval, Ws[k * 16 + c], acc[c]);
        }
    }
    #pragma unroll
    for (int c = 0; c < 16; ++c) {
        acc[c] += __shfl_down(acc[c], 16);
        acc[c] += __shfl_down(acc[c], 32);
    }
    if (lane < 16 && row < M) {
        float* orow = C + (size_t)row * 16;
        #pragma unroll
        for (int c = 0; c < 16; c += 4) {
            float4 v = make_float4(acc[c] + bh[c], acc[c + 1] + bh[c + 1],
                                   acc[c + 2] + bh[c + 2], acc[c + 3] + bh[c + 3]);
            *(float4*)(orow + c) = v;
        }
    }
}

// ---------------- launch ----------------

extern "C" void kernel_launch(void* const* d_in, const int* in_sizes, int n_in,
                              void* d_out, int out_size, void* d_ws, size_t ws_size,
                              hipStream_t stream) {
    const float* x  = (const float*)d_in[0];
    const float* W1 = (const float*)d_in[1];
    const float* b1 = (const float*)d_in[2];
    const float* W2 = (const float*)d_in[3];
    const float* b2 = (const float*)d_in[4];
    const float* Wh = (const float*)d_in[5];
    const float* bh = (const float*)d_in[6];
    const int*   ei = (const int*)d_in[7];

    const int N = in_sizes[0] / 128;
    const int E = in_sizes[7] / 2;
    const int* src = ei;
    const int* dst = ei + E;
    float* out = (float*)d_out;

    char* w = (char*)d_ws;
    auto alloc = [&](size_t bytes) -> void* {
        void* p = (void*)w;
        w += (bytes + 255) & ~(size_t)255;
        return p;
    };
    unsigned short* actA      = (unsigned short*)alloc((size_t)N * 128 * sizeof(short));
    unsigned short* hp        = (unsigned short*)alloc((size_t)N * 128 * sizeof(short));
    unsigned short* actB      = (unsigned short*)alloc((size_t)N * 128 * sizeof(short));
    int*   indeg     = (int*)alloc((size_t)N * sizeof(int));
    int*   row_start = (int*)alloc((size_t)(N + 1) * sizeof(int));
    float* dinv      = (float*)alloc((size_t)N * sizeof(float));
    int*   tilesums  = (int*)alloc(128 * sizeof(int));
    int*   edge_src  = (int*)alloc((size_t)E * sizeof(int));
    int*   rank      = (int*)alloc((size_t)E * sizeof(int));
    short* w1hiP     = (short*)alloc(128 * 128 * sizeof(short));
    short* w1loP     = (short*)alloc(128 * 128 * sizeof(short));
    short* w2hiP     = (short*)alloc(128 * 128 * sizeof(short));
    short* w2loP     = (short*)alloc(128 * 128 * sizeof(short));

    hipMemsetAsync(indeg, 0, (size_t)N * sizeof(int), stream);

    // CSR build (graph identical for both layers)
    k_count_rank<<<(E + 255) / 256, 256, 0, stream>>>(dst, indeg, rank, E);
    const int nTiles = (N + 1023) / 1024;
    k_scan1<<<nTiles, 256, 0, stream>>>(indeg, row_start, tilesums, N);
    k_scan2<<<1, 128, 0, stream>>>(tilesums, nTiles);
    k_scan3_dinv<<<(N + 255) / 256, 256, 0, stream>>>(row_start, tilesums, indeg, dinv, N, E);
    k_fill_rank<<<(E + 255) / 256, 256, 0, stream>>>(src, dst, rank, row_start, edge_src, E);

    // weight splits (panel layout) + x convert
    k_wsplit_panel<<<8, 256, 0, stream>>>(W1, w1hiP, w1loP);
    k_wsplit_panel<<<8, 256, 0, stream>>>(W2, w2hiP, w2loP);
    const int total8 = N * 16;   // N*128/8
    k_xbf16<<<(total8 + 255) / 256, 256, 0, stream>>>(x, actA, total8);

    const int gblocks = (N + 127) / 128;
    const int ablocks = (N + 15) / 16;
    // layer 1
    k_gemm_mfma<<<gblocks, 256, 0, stream>>>(actA, w1hiP, w1loP, dinv, hp, N);
    k_aggregate<<<ablocks, 256, 0, stream>>>(hp, row_start, edge_src, dinv, b1, actB, N);
    // layer 2
    k_gemm_mfma<<<gblocks, 256, 0, stream>>>(actB, w2hiP, w2loP, dinv, hp, N);
    k_aggregate<<<ablocks, 256, 0, stream>>>(hp, row_start, edge_src, dinv, b2, actA, N);
    // head
    k_gemm_head<<<(N + 63) / 64, 256, 0, stream>>>(actA, Wh, bh, out, N);
}

// Round 8
// 196.181 us; speedup vs baseline: 1.8644x; 1.0661x over previous
//
#include <hip/hip_runtime.h>
#include <hip/hip_bf16.h>

typedef short bf16x8 __attribute__((ext_vector_type(8)));
typedef unsigned short u16x8 __attribute__((ext_vector_type(8)));
typedef float f32x4 __attribute__((ext_vector_type(4)));

// ---------- bf16 helpers ----------
static __device__ __forceinline__ short f2bf(float f) {
    union { float f; unsigned u; } v; v.f = f;
    unsigned r = v.u + 0x7FFF + ((v.u >> 16) & 1);   // RNE
    return (short)(r >> 16);
}
static __device__ __forceinline__ float bf2f(short h) {
    union { unsigned u; float f; } v;
    v.u = ((unsigned)(unsigned short)h) << 16;
    return v.f;
}
static __device__ __forceinline__ float bfu2f(unsigned short h) {
    union { unsigned u; float f; } v;
    v.u = ((unsigned)h) << 16;
    return v.f;
}

// ---------------- fused prep: count_rank || x->bf16 || 2x weight panel split -------
// Independent writes; blockIdx-range dispatch overlaps latency-bound atomics with
// BW-bound conversion.

__global__ __launch_bounds__(256) void k_prep(
    const int* __restrict__ dst, int* __restrict__ indeg, int* __restrict__ rank,
    int E, int nbE,
    const float* __restrict__ X, unsigned short* __restrict__ Xbf, int total8, int nbX,
    const float* __restrict__ W1, short* __restrict__ b1hi, short* __restrict__ b1lo,
    const float* __restrict__ W2, short* __restrict__ b2hi, short* __restrict__ b2lo) {
    const int b = blockIdx.x;
    const int t = threadIdx.x;
    if (b < nbE) {
        // edge histogram + per-edge rank (atomic return value)
        int e = b * 256 + t;
        if (e < E) rank[e] = atomicAdd(&indeg[dst[e]], 1);
    } else if (b < nbE + nbX) {
        // x fp32 -> bf16
        int idx = (b - nbE) * 256 + t;
        if (idx < total8) {
            float4 v0 = ((const float4*)X)[idx * 2];
            float4 v1 = ((const float4*)X)[idx * 2 + 1];
            u16x8 o;
            o[0] = (unsigned short)f2bf(v0.x); o[1] = (unsigned short)f2bf(v0.y);
            o[2] = (unsigned short)f2bf(v0.z); o[3] = (unsigned short)f2bf(v0.w);
            o[4] = (unsigned short)f2bf(v1.x); o[5] = (unsigned short)f2bf(v1.y);
            o[6] = (unsigned short)f2bf(v1.z); o[7] = (unsigned short)f2bf(v1.w);
            ((u16x8*)Xbf)[idx] = o;
        }
    } else {
        // weight split -> panel layout: unit u = nb*256 + k8*16 + c16 holds
        // W[k8*8 .. +8][nb*16+c16] hi/lo. Wave B-fragment load = 1KB contiguous.
        int wb = b - nbE - nbX;                 // 0..15
        const float* W = (wb < 8) ? W1 : W2;
        short* BH = (wb < 8) ? b1hi : b2hi;
        short* BL = (wb < 8) ? b1lo : b2lo;
        int u = (wb & 7) * 256 + t;             // 0..2047
        int nb = u >> 8, k8 = (u >> 4) & 15, c16 = u & 15;
        int col = nb * 16 + c16, k0 = k8 * 8;
        bf16x8 h, l;
        #pragma unroll
        for (int j = 0; j < 8; ++j) {
            float v = W[(size_t)(k0 + j) * 128 + col];
            short hh = f2bf(v);
            h[j] = hh;
            l[j] = f2bf(v - bf2f(hh));
        }
        *(bf16x8*)(BH + (size_t)u * 8) = h;
        *(bf16x8*)(BL + (size_t)u * 8) = l;
    }
}

// ---------------- scans ----------------

__global__ void k_scan1(const int* __restrict__ in, int* __restrict__ out,
                        int* __restrict__ sums, int n) {
    __shared__ int lds[256];
    const int t = threadIdx.x;
    const int base = blockIdx.x * 1024 + t * 4;
    int v0 = (base + 0 < n) ? in[base + 0] : 0;
    int v1 = (base + 1 < n) ? in[base + 1] : 0;
    int v2 = (base + 2 < n) ? in[base + 2] : 0;
    int v3 = (base + 3 < n) ? in[base + 3] : 0;
    const int tsum = v0 + v1 + v2 + v3;
    lds[t] = tsum;
    __syncthreads();
    #pragma unroll
    for (int off = 1; off < 256; off <<= 1) {
        int x = (t >= off) ? lds[t - off] : 0;
        __syncthreads();
        lds[t] += x;
        __syncthreads();
    }
    int excl = lds[t] - tsum;
    if (base + 0 < n) out[base + 0] = excl;  excl += v0;
    if (base + 1 < n) out[base + 1] = excl;  excl += v1;
    if (base + 2 < n) out[base + 2] = excl;  excl += v2;
    if (base + 3 < n) out[base + 3] = excl;
    if (t == 255) sums[blockIdx.x] = lds[255];
}

__global__ void k_scan2(int* __restrict__ sums, int nt) {
    __shared__ int lds[128];
    const int t = threadIdx.x;
    int v = (t < nt) ? sums[t] : 0;
    lds[t] = v;
    __syncthreads();
    #pragma unroll
    for (int off = 1; off < 128; off <<= 1) {
        int x = (t >= off) ? lds[t - off] : 0;
        __syncthreads();
        lds[t] += x;
        __syncthreads();
    }
    if (t < nt) sums[t] = lds[t] - v;
}

__global__ void k_scan3_dinv(int* __restrict__ row_start, const int* __restrict__ sums,
                             const int* __restrict__ indeg, float* __restrict__ dinv,
                             int n, int E) {
    int i = blockIdx.x * 256 + threadIdx.x;
    if (i < n) {
        row_start[i] += sums[i >> 10];
        dinv[i] = rsqrtf((float)indeg[i] + 1.0f);   // +1 self-loop
    }
    if (i == 0) row_start[n] = E;
}

// ---------------- MFMA GEMM body (shared by fused and standalone kernels) --------
// A staged through LDS: coalesced 16B/lane global loads, XOR-swizzled ds_write/read
// (unit = row*16 + (chunk ^ (row&7)), 2-way banks max). B from panel layout: fully
// coalesced 1KB register loads, double-buffered. 2-term: A bf16 exact, B hi+lo.

static __device__ __forceinline__ void gemm_body(
    unsigned short* As,                         // 128*128 shared
    const unsigned short* __restrict__ Abf,
    const short* __restrict__ Bp_hi, const short* __restrict__ Bp_lo,
    const float* __restrict__ dinv, unsigned short* __restrict__ Cbf,
    int M, int bid) {
    const int tid  = threadIdx.x;
    const int wave = tid >> 6;
    const int lane = tid & 63;
    const int r16  = lane & 15;
    const int kg   = lane >> 4;                 // k-group 0..3
    const int m0   = bid * 128;
    const int mh   = (wave >> 1) * 64;          // m-half base within tile
    const int nb0  = (wave & 1) * 4;            // n-half: panel blocks 0..3 / 4..7

    // ---- stage A tile: 8 rounds x 256 threads x 16B, coalesced ----
    #pragma unroll
    for (int rr = 0; rr < 8; ++rr) {
        int u = rr * 256 + tid;
        int row = u >> 4, c = u & 15;
        int rowg = m0 + row;
        if (rowg >= M) rowg = M - 1;
        bf16x8 v = *(const bf16x8*)(Abf + (size_t)rowg * 128 + c * 8);
        *(bf16x8*)(As + (size_t)(row * 16 + (c ^ (row & 7))) * 8) = v;
    }

    // ---- prefetch B kstep 0 (contiguous 1KB per instr, L2-resident) ----
    bf16x8 bufh[2][4], bufl[2][4];
    #pragma unroll
    for (int ni = 0; ni < 4; ++ni) {
        size_t uB = (size_t)(nb0 + ni) * 256 + (size_t)kg * 16 + r16;
        bufh[0][ni] = *(const bf16x8*)(Bp_hi + uB * 8);
        bufl[0][ni] = *(const bf16x8*)(Bp_lo + uB * 8);
    }

    __syncthreads();

    f32x4 acc[4][4] = {};

    #pragma unroll
    for (int ks = 0; ks < 4; ++ks) {
        const int cur = ks & 1, nxt = cur ^ 1;
        if (ks < 3) {
            #pragma unroll
            for (int ni = 0; ni < 4; ++ni) {
                size_t uB = (size_t)(nb0 + ni) * 256 + (size_t)((ks + 1) * 4 + kg) * 16 + r16;
                bufh[nxt][ni] = *(const bf16x8*)(Bp_hi + uB * 8);
                bufl[nxt][ni] = *(const bf16x8*)(Bp_lo + uB * 8);
            }
        }
        // A fragments from LDS (swizzled)
        bf16x8 a[4];
        const int c = ks * 4 + kg;
        #pragma unroll
        for (int mi = 0; mi < 4; ++mi) {
            int row = mh + mi * 16 + r16;
            a[mi] = *(const bf16x8*)(As + (size_t)(row * 16 + (c ^ (row & 7))) * 8);
        }
        #pragma unroll
        for (int mi = 0; mi < 4; ++mi)
            #pragma unroll
            for (int ni = 0; ni < 4; ++ni) {
                acc[mi][ni] = __builtin_amdgcn_mfma_f32_16x16x32_bf16(a[mi], bufl[cur][ni], acc[mi][ni], 0, 0, 0);
                acc[mi][ni] = __builtin_amdgcn_mfma_f32_16x16x32_bf16(a[mi], bufh[cur][ni], acc[mi][ni], 0, 0, 0);
            }
    }

    // epilogue: D layout col=lane&15, row=(lane>>4)*4+reg ; scale by dinv[row], cast bf16
    const int n0 = (wave & 1) * 64;
    #pragma unroll
    for (int mi = 0; mi < 4; ++mi) {
        #pragma unroll
        for (int r = 0; r < 4; ++r) {
            int row = m0 + mh + mi * 16 + (lane >> 4) * 4 + r;
            if (row < M) {
                float dr = dinv[row];
                #pragma unroll
                for (int ni = 0; ni < 4; ++ni) {
                    int col = n0 + ni * 16 + r16;
                    Cbf[(size_t)row * 128 + col] = (unsigned short)f2bf(acc[mi][ni][r] * dr);
                }
            }
        }
    }
}

// fused: layer-1 GEMM || CSR fill (independent stages, same launch)
__global__ __launch_bounds__(256) void k_gemm_fill(
    const unsigned short* __restrict__ Abf,
    const short* __restrict__ Bp_hi, const short* __restrict__ Bp_lo,
    const float* __restrict__ dinv, unsigned short* __restrict__ Cbf,
    int M, int gblocks,
    const int* __restrict__ src, const int* __restrict__ dstv,
    const int* __restrict__ rank, const int* __restrict__ row_start,
    int* __restrict__ edge_src, int E) {
    __shared__ unsigned short As[128 * 128];    // 32 KB
    if (blockIdx.x >= gblocks) {
        int e = (blockIdx.x - gblocks) * 256 + threadIdx.x;
        if (e < E) edge_src[row_start[dstv[e]] + rank[e]] = src[e];
        return;
    }
    gemm_body(As, Abf, Bp_hi, Bp_lo, dinv, Cbf, M, blockIdx.x);
}

// standalone (layer 2)
__global__ __launch_bounds__(256) void k_gemm_mfma(
    const unsigned short* __restrict__ Abf,
    const short* __restrict__ Bp_hi, const short* __restrict__ Bp_lo,
    const float* __restrict__ dinv, unsigned short* __restrict__ Cbf, int M) {
    __shared__ unsigned short As[128 * 128];
    gemm_body(As, Abf, Bp_hi, Bp_lo, dinv, Cbf, M, blockIdx.x);
}

// ---------------- aggregation: 4 nodes/wave, 16 lanes x ushort8, 8-wide gather ----
// outBf[i,:] = bf16( relu( dinv[i] * ( h'[i,:] + sum_{e: dst=i} h'[src_e,:] ) + b ) )

__global__ __launch_bounds__(256) void k_aggregate(const unsigned short* __restrict__ hp,
                                                   const int* __restrict__ row_start,
                                                   const int* __restrict__ edge_src,
                                                   const float* __restrict__ dinv,
                                                   const float* __restrict__ bias,
                                                   unsigned short* __restrict__ outBf, int n) {
    const int wave = (blockIdx.x * 256 + threadIdx.x) >> 6;
    const int sub  = (threadIdx.x >> 4) & 3;
    const int l16  = threadIdx.x & 15;
    const int i    = wave * 4 + sub;
    if (i >= n) return;

    const u16x8* __restrict__ h8 = (const u16x8*)hp;   // 16 x u16x8 per row

    u16x8 sv = h8[(size_t)i * 16 + l16];               // self term
    float a[8], b[8];
    #pragma unroll
    for (int q = 0; q < 8; ++q) { a[q] = bfu2f(sv[q]); b[q] = 0.f; }

    int j = row_start[i];
    const int e = row_start[i + 1];
    while (j < e) {
        const int e1 = e - 1;
        int   idx[8];
        float m[8];
        #pragma unroll
        for (int t = 0; t < 8; ++t) {
            int jt = j + t;
            bool ct = jt < e;
            idx[t] = edge_src[ct ? jt : e1];
            m[t] = ct ? 1.f : 0.f;
        }
        u16x8 v[8];
        #pragma unroll
        for (int t = 0; t < 8; ++t) v[t] = h8[(size_t)idx[t] * 16 + l16];
        #pragma unroll
        for (int t = 0; t < 8; t += 2) {
            #pragma unroll
            for (int q = 0; q < 8; ++q) {
                a[q] = fmaf(bfu2f(v[t][q]),     m[t],     a[q]);
                b[q] = fmaf(bfu2f(v[t + 1][q]), m[t + 1], b[q]);
            }
        }
        j += 8;
    }

    const float di = dinv[i];
    float4 bs0 = ((const float4*)bias)[l16 * 2];
    float4 bs1 = ((const float4*)bias)[l16 * 2 + 1];
    float bb[8] = {bs0.x, bs0.y, bs0.z, bs0.w, bs1.x, bs1.y, bs1.z, bs1.w};
    u16x8 ov;
    #pragma unroll
    for (int q = 0; q < 8; ++q) {
        float r = fmaxf(fmaf(a[q] + b[q], di, bb[q]), 0.f);
        ov[q] = (unsigned short)f2bf(r);
    }
    ((u16x8*)outBf)[(size_t)i * 16 + l16] = ov;
}

// ---------------- head GEMM: out[M x 16] = bf16A[M x 128] * Wh[128 x 16] + bh ----------

__global__ __launch_bounds__(256) void k_gemm_head(const unsigned short* __restrict__ A,
                                                   const float* __restrict__ Wh,
                                                   const float* __restrict__ bh,
                                                   float* __restrict__ C, int M) {
    __shared__ float Ws[128 * 16];
    const int t = threadIdx.x;
    *(float4*)&Ws[t * 8]     = *(const float4*)&Wh[t * 8];
    *(float4*)&Ws[t * 8 + 4] = *(const float4*)&Wh[t * 8 + 4];
    __syncthreads();

    const int wave = t >> 6;
    const int lane = t & 63;
    const int r    = lane & 15;
    const int kq   = lane >> 4;
    int row = (blockIdx.x * 4 + wave) * 16 + r;
    int lrow = (row < M) ? row : (M - 1);

    const u16x8* ap = (const u16x8*)(A + (size_t)lrow * 128 + kq * 32);
    float acc[16] = {};
    #pragma unroll
    for (int k8 = 0; k8 < 4; ++k8) {
        u16x8 av = ap[k8];
        #pragma unroll
        for (int q = 0; q < 8; ++q) {
            int k = kq * 32 + k8 * 8 + q;
            float aval = bfu2f(av[q]);
            #pragma unroll
            for (int c = 0; c < 16; ++c)
                acc[c] = fmaf(aval, Ws[k * 16 + c], acc[c]);
        }
    }
    #pragma unroll
    for (int c = 0; c < 16; ++c) {
        acc[c] += __shfl_down(acc[c], 16);
        acc[c] += __shfl_down(acc[c], 32);
    }
    if (lane < 16 && row < M) {
        float* orow = C + (size_t)row * 16;
        #pragma unroll
        for (int c = 0; c < 16; c += 4) {
            float4 v = make_float4(acc[c] + bh[c], acc[c + 1] + bh[c + 1],
                                   acc[c + 2] + bh[c + 2], acc[c + 3] + bh[c + 3]);
            *(float4*)(orow + c) = v;
        }
    }
}

// ---------------- launch ----------------

extern "C" void kernel_launch(void* const* d_in, const int* in_sizes, int n_in,
                              void* d_out, int out_size, void* d_ws, size_t ws_size,
                              hipStream_t stream) {
    const float* x  = (const float*)d_in[0];
    const float* W1 = (const float*)d_in[1];
    const float* b1 = (const float*)d_in[2];
    const float* W2 = (const float*)d_in[3];
    const float* b2 = (const float*)d_in[4];
    const float* Wh = (const float*)d_in[5];
    const float* bh = (const float*)d_in[6];
    const int*   ei = (const int*)d_in[7];

    const int N = in_sizes[0] / 128;
    const int E = in_sizes[7] / 2;
    const int* src = ei;
    const int* dst = ei + E;
    float* out = (float*)d_out;

    char* w = (char*)d_ws;
    auto alloc = [&](size_t bytes) -> void* {
        void* p = (void*)w;
        w += (bytes + 255) & ~(size_t)255;
        return p;
    };
    unsigned short* actA      = (unsigned short*)alloc((size_t)N * 128 * sizeof(short));
    unsigned short* hp        = (unsigned short*)alloc((size_t)N * 128 * sizeof(short));
    unsigned short* actB      = (unsigned short*)alloc((size_t)N * 128 * sizeof(short));
    int*   indeg     = (int*)alloc((size_t)N * sizeof(int));
    int*   row_start = (int*)alloc((size_t)(N + 1) * sizeof(int));
    float* dinv      = (float*)alloc((size_t)N * sizeof(float));
    int*   tilesums  = (int*)alloc(128 * sizeof(int));
    int*   edge_src  = (int*)alloc((size_t)E * sizeof(int));
    int*   rank      = (int*)alloc((size_t)E * sizeof(int));
    short* w1hiP     = (short*)alloc(128 * 128 * sizeof(short));
    short* w1loP     = (short*)alloc(128 * 128 * sizeof(short));
    short* w2hiP     = (short*)alloc(128 * 128 * sizeof(short));
    short* w2loP     = (short*)alloc(128 * 128 * sizeof(short));

    hipMemsetAsync(indeg, 0, (size_t)N * sizeof(int), stream);

    const int total8 = N * 16;                  // N*128/8
    const int nbE = (E + 255) / 256;
    const int nbX = (total8 + 255) / 256;
    // prep: count_rank || x->bf16 || weight splits
    k_prep<<<nbE + nbX + 16, 256, 0, stream>>>(dst, indeg, rank, E, nbE,
                                               x, actA, total8, nbX,
                                               W1, w1hiP, w1loP, W2, w2hiP, w2loP);
    const int nTiles = (N + 1023) / 1024;
    k_scan1<<<nTiles, 256, 0, stream>>>(indeg, row_start, tilesums, N);
    k_scan2<<<1, 128, 0, stream>>>(tilesums, nTiles);
    k_scan3_dinv<<<(N + 255) / 256, 256, 0, stream>>>(row_start, tilesums, indeg, dinv, N, E);

    const int gblocks = (N + 127) / 128;
    const int ablocks = (N + 15) / 16;
    // layer-1 GEMM || CSR fill
    k_gemm_fill<<<gblocks + nbE, 256, 0, stream>>>(actA, w1hiP, w1loP, dinv, hp, N, gblocks,
                                                   src, dst, rank, row_start, edge_src, E);
    k_aggregate<<<ablocks, 256, 0, stream>>>(hp, row_start, edge_src, dinv, b1, actB, N);
    // layer 2
    k_gemm_mfma<<<gblocks, 256, 0, stream>>>(actB, w2hiP, w2loP, dinv, hp, N);
    k_aggregate<<<ablocks, 256, 0, stream>>>(hp, row_start, edge_src, dinv, b2, actA, N);
    // head
    k_gemm_head<<<(N + 63) / 64, 256, 0, stream>>>(actA, Wh, bh, out, N);
}